// Round 33
// baseline (263.641 us; speedup 1.0000x reference)
//
#include <hip/hip_runtime.h>
#include <math.h>

// Problem constants
#define BB 4
#define SS 1024
#define DD 768
#define HH 12
#define DHD 64
#define MROWS 4096
#define FF 3072
#define WPC (DD * DD)

typedef unsigned short u16;
typedef float f32x4 __attribute__((ext_vector_type(4)));
typedef __bf16 bf16x8 __attribute__((ext_vector_type(8)));
typedef unsigned short u16x8 __attribute__((ext_vector_type(8)));
typedef unsigned short u16x4 __attribute__((ext_vector_type(4)));

static __device__ __forceinline__ float bf2f(u16 u) {
    union { unsigned int i; float f; } c; c.i = ((unsigned int)u) << 16; return c.f;
}
static __device__ __forceinline__ u16 f2bf(float f) {
    return __builtin_bit_cast(u16, static_cast<__bf16>(f));
}
// XCD-chunked swizzle: flat grid, total % 8 == 0.
static __device__ __forceinline__ int xcd_swz(int total) {
    const int bid = (int)blockIdx.x;
    return (bid & 7) * (total >> 3) + (bid >> 3);
}
// Async global->LDS, 16B per lane.
static __device__ __forceinline__ void gload16(const u16* g, u16* l) {
    __builtin_amdgcn_global_load_lds(
        (const __attribute__((address_space(1))) void*)g,
        (__attribute__((address_space(3))) void*)l, 16, 0, 0);
}
// GELU tanh-form via sigmoid: x*sigmoid(1.5958(x+0.044715x^3)).
// exp2-domain, hw rcp. Max abs error vs exact erf-GELU ~3e-4.
static __device__ __forceinline__ float gelu_f(float x) {
    const float x2 = x * x;
    const float t  = x * fmaf(x2, -0.10294437f, -2.30220800f);
    return x * __builtin_amdgcn_rcpf(1.0f + exp2f(t));
}

// Balanced causal q-tile map (R29-validated). Co-resident blocks on a CU are
// lids {L, L+32, L+64}; entry = qt | (B<<4); each triple sums nkt 13-14.
// XCD L2 locality preserved (R30 lesson: dynamic assignment destroys it).
static __device__ const unsigned char QBTAB[48] = {
    15,  7,  3,
    14,  6,  2,
    31, 23,  1,
    30, 22,  0,
    47,  5, 19,
    46,  4, 18,
    13, 11, 17,
    12, 10, 16,
    29,  9, 35,
    28,  8, 34,
    45, 25, 33,
    44, 24, 32,
    27, 41, 21,
    26, 40, 20,
    43, 39, 37,
    42, 38, 36,
};

// ---------------------------------------------------------------------------
// 128x128-tile bf16 MFMA GEMM core, async staging, BK=64 dual k-half buffers.
// (BK=128 would need 64KB LDS -> occupancy loss; R32 falsified it for gemm64
// too: 49KB dropped 6->3 blocks/CU and erased the barrier savings.)
// ---------------------------------------------------------------------------
static __device__ __forceinline__ void gemm128_core(
    const u16* __restrict__ A, const u16* __restrict__ Bt,
    int K,
    const float* __restrict__ bias, int do_gelu,
    u16* __restrict__ Cbf, int ldcbf, int cboff,
    int row0, int col0, u16* As0, u16* As1, u16* Bs0, u16* Bs1)
{
    const int tid  = threadIdx.x;
    const int lane = tid & 63;
    const int w    = tid >> 6;
    const int wm = (w >> 1) * 64;
    const int wn = (w & 1) * 64;

    const u16* Ap = A  + (size_t)(row0 + w * 32 + (lane >> 2)) * K + (lane & 3) * 8;
    const u16* Bp = Bt + (size_t)(col0 + w * 32 + (lane >> 2)) * K + (lane & 3) * 8;
    const int woff = (w * 32) * 32;

    const int fr = lane & 15;
    const int fk = (lane >> 4) * 8;
    const int afo = (wm + fr) * 32 + fk;
    const int bfo = (wn + fr) * 32 + fk;

    f32x4 acc[4][4] = {};

    for (int k0 = 0; k0 < K; k0 += 64) {
        if (k0) __syncthreads();
        gload16(Ap + k0,               As0 + woff);
        gload16(Ap + k0 + 16 * K,      As0 + woff + 16 * 32);
        gload16(Ap + k0 + 32,          As1 + woff);
        gload16(Ap + k0 + 32 + 16 * K, As1 + woff + 16 * 32);
        gload16(Bp + k0,               Bs0 + woff);
        gload16(Bp + k0 + 16 * K,      Bs0 + woff + 16 * 32);
        gload16(Bp + k0 + 32,          Bs1 + woff);
        gload16(Bp + k0 + 32 + 16 * K, Bs1 + woff + 16 * 32);
        __syncthreads();

        {
            bf16x8 af[4], bfv[4];
#pragma unroll
            for (int mi = 0; mi < 4; ++mi)
                af[mi] = __builtin_bit_cast(bf16x8,
                    *(const u16x8*)(As0 + afo + mi * 16 * 32));
#pragma unroll
            for (int ni = 0; ni < 4; ++ni)
                bfv[ni] = __builtin_bit_cast(bf16x8,
                    *(const u16x8*)(Bs0 + bfo + ni * 16 * 32));
#pragma unroll
            for (int mi = 0; mi < 4; ++mi)
#pragma unroll
                for (int ni = 0; ni < 4; ++ni)
                    acc[mi][ni] = __builtin_amdgcn_mfma_f32_16x16x32_bf16(
                        af[mi], bfv[ni], acc[mi][ni], 0, 0, 0);
        }
        {
            bf16x8 af[4], bfv[4];
#pragma unroll
            for (int mi = 0; mi < 4; ++mi)
                af[mi] = __builtin_bit_cast(bf16x8,
                    *(const u16x8*)(As1 + afo + mi * 16 * 32));
#pragma unroll
            for (int ni = 0; ni < 4; ++ni)
                bfv[ni] = __builtin_bit_cast(bf16x8,
                    *(const u16x8*)(Bs1 + bfo + ni * 16 * 32));
#pragma unroll
            for (int mi = 0; mi < 4; ++mi)
#pragma unroll
                for (int ni = 0; ni < 4; ++ni)
                    acc[mi][ni] = __builtin_amdgcn_mfma_f32_16x16x32_bf16(
                        af[mi], bfv[ni], acc[mi][ni], 0, 0, 0);
        }
    }

    const int orow0 = row0 + wm + (lane >> 4) * 4;
    const int ocol0 = col0 + wn + fr;
#pragma unroll
    for (int mi = 0; mi < 4; ++mi) {
#pragma unroll
        for (int ni = 0; ni < 4; ++ni) {
            const int col = ocol0 + ni * 16;
            const float bv = bias ? bias[col] : 0.0f;
#pragma unroll
            for (int r = 0; r < 4; ++r) {
                const int row = orow0 + mi * 16 + r;
                float v = acc[mi][ni][r] + bv;
                if (do_gelu) v = gelu_f(v);
                Cbf[(size_t)row * ldcbf + cboff + col] = f2bf(v);
            }
        }
    }
}

// MLP1: flat 768-block grid, XCD-swizzled.
__global__ __launch_bounds__(256) void gemm128_mlp1(
    const u16* __restrict__ A, const u16* __restrict__ Bt,
    const float* __restrict__ bias, u16* __restrict__ Cbf)
{
    __shared__ u16 As0[128 * 32];
    __shared__ u16 As1[128 * 32];
    __shared__ u16 Bs0[128 * 32];
    __shared__ u16 Bs1[128 * 32];
    const int lid = xcd_swz(24 * 32);
    gemm128_core(A, Bt, DD, bias, 1, Cbf, FF, 0,
                 (lid / 24) * 128, (lid % 24) * 128, As0, As1, Bs0, Bs1);
}

// Batched independent projections, flat 960-block grid, XCD-swizzled.
__global__ __launch_bounds__(256) void gemm128_proj(
    const u16* __restrict__ BFx, const u16* __restrict__ BFK,
    const u16* __restrict__ BFV, const u16* __restrict__ Wm6,
    u16* __restrict__ QKV, u16* __restrict__ KVc)
{
    __shared__ u16 As0[128 * 32];
    __shared__ u16 As1[128 * 32];
    __shared__ u16 Bs0[128 * 32];
    __shared__ u16 Bs1[128 * 32];
    const int fid = xcd_swz(960);
    const u16* A; const u16* B; u16* C; int ldc, coff, row0, col0;
    if (fid < 576) {
        A = BFx; B = Wm6; C = QKV; ldc = 3 * DD; coff = 0;
        row0 = (fid / 18) * 128; col0 = (fid % 18) * 128;
    } else if (fid < 768) {
        const int l = fid - 576;
        A = BFK; B = Wm6 + 4 * WPC; C = KVc; ldc = 2 * DD; coff = 0;
        row0 = (l / 6) * 128; col0 = (l % 6) * 128;
    } else {
        const int l = fid - 768;
        A = BFV; B = Wm6 + 5 * WPC; C = KVc; ldc = 2 * DD; coff = DD;
        row0 = (l / 6) * 128; col0 = (l % 6) * 128;
    }
    gemm128_core(A, B, DD, nullptr, 0, C, ldc, coff, row0, col0,
                 As0, As1, Bs0, Bs1);
}

// ---------------------------------------------------------------------------
// 64x128-tile GEMM core, async staging, BK=64 dual k-half buffers
// (R31-exact; R32's BK=128 quad-buffer regressed via occupancy 6->3).
// ---------------------------------------------------------------------------
static __device__ __forceinline__ void gemm64_core(
    const u16* __restrict__ A, const u16* __restrict__ Bt,
    int N, int Kstride, int Klen,
    u16* __restrict__ Cbf, int ldcbf, int cboff,
    int row0, int col0, u16* As0, u16* As1, u16* Bs0, u16* Bs1)
{
    const int tid  = threadIdx.x;
    const int lane = tid & 63;
    const int w    = tid >> 6;
    const int wm = (w >> 1) * 32;
    const int wn = (w & 1) * 64;

    const u16* Ap = A  + (size_t)(row0 + w * 16 + (lane >> 2)) * Kstride + (lane & 3) * 8;
    const u16* Bp = Bt + (size_t)(col0 + w * 32 + (lane >> 2)) * Kstride + (lane & 3) * 8;
    const int aoff = (w * 16) * 32;
    const int boff = (w * 32) * 32;

    const int fr = lane & 15;
    const int fk = (lane >> 4) * 8;
    const int afo = (wm + fr) * 32 + fk;
    const int bfo = (wn + fr) * 32 + fk;

    f32x4 acc[2][4] = {};

    for (int k0 = 0; k0 < Klen; k0 += 64) {
        if (k0) __syncthreads();
        gload16(Ap + k0,                     As0 + aoff);
        gload16(Ap + k0 + 32,                As1 + aoff);
        gload16(Bp + k0,                     Bs0 + boff);
        gload16(Bp + k0 + 16 * Kstride,      Bs0 + boff + 16 * 32);
        gload16(Bp + k0 + 32,                Bs1 + boff);
        gload16(Bp + k0 + 32 + 16 * Kstride, Bs1 + boff + 16 * 32);
        __syncthreads();

        {
            bf16x8 af[2], bfv[4];
#pragma unroll
            for (int mi = 0; mi < 2; ++mi)
                af[mi] = __builtin_bit_cast(bf16x8,
                    *(const u16x8*)(As0 + afo + mi * 16 * 32));
#pragma unroll
            for (int ni = 0; ni < 4; ++ni)
                bfv[ni] = __builtin_bit_cast(bf16x8,
                    *(const u16x8*)(Bs0 + bfo + ni * 16 * 32));
#pragma unroll
            for (int mi = 0; mi < 2; ++mi)
#pragma unroll
                for (int ni = 0; ni < 4; ++ni)
                    acc[mi][ni] = __builtin_amdgcn_mfma_f32_16x16x32_bf16(
                        af[mi], bfv[ni], acc[mi][ni], 0, 0, 0);
        }
        {
            bf16x8 af[2], bfv[4];
#pragma unroll
            for (int mi = 0; mi < 2; ++mi)
                af[mi] = __builtin_bit_cast(bf16x8,
                    *(const u16x8*)(As1 + afo + mi * 16 * 32));
#pragma unroll
            for (int ni = 0; ni < 4; ++ni)
                bfv[ni] = __builtin_bit_cast(bf16x8,
                    *(const u16x8*)(Bs1 + bfo + ni * 16 * 32));
#pragma unroll
            for (int mi = 0; mi < 2; ++mi)
#pragma unroll
                for (int ni = 0; ni < 4; ++ni)
                    acc[mi][ni] = __builtin_amdgcn_mfma_f32_16x16x32_bf16(
                        af[mi], bfv[ni], acc[mi][ni], 0, 0, 0);
        }
    }

    const int orow0 = row0 + wm + (lane >> 4) * 4;
    const int ocol0 = col0 + wn + fr;
#pragma unroll
    for (int mi = 0; mi < 2; ++mi) {
#pragma unroll
        for (int ni = 0; ni < 4; ++ni) {
            const int col = ocol0 + ni * 16;
#pragma unroll
            for (int r = 0; r < 4; ++r) {
                const int row = orow0 + mi * 16 + r;
                Cbf[(size_t)row * ldcbf + cboff + col] = f2bf(acc[mi][ni][r]);
            }
        }
    }
}

// Cross-Q projection: N=K=768, output strided into QKV. 384 blocks.
__global__ __launch_bounds__(256) void gemm64(
    const u16* __restrict__ A, const u16* __restrict__ Bt,
    u16* __restrict__ Cbf, int ldcbf)
{
    __shared__ u16 As0[64 * 32];
    __shared__ u16 As1[64 * 32];
    __shared__ u16 Bs0[128 * 32];
    __shared__ u16 Bs1[128 * 32];
    const int lid = xcd_swz(6 * 64);
    gemm64_core(A, Bt, DD, DD, DD, Cbf, ldcbf, 0,
                (lid / 6) * 64, (lid % 6) * 128, As0, As1, Bs0, Bs1);
}

// Split-K x2 GEMM (Wo / MLP2): 768 blocks; bf16 partials to Cpair.
__global__ __launch_bounds__(256) void gemm64_sk(
    const u16* __restrict__ A, const u16* __restrict__ Bt,
    int Kstride, int Khalf, u16* __restrict__ Cpair)
{
    __shared__ u16 As0[64 * 32];
    __shared__ u16 As1[64 * 32];
    __shared__ u16 Bs0[128 * 32];
    __shared__ u16 Bs1[128 * 32];
    const int lid = xcd_swz(6 * 64 * 2);
    const int x = lid % 6;
    const int rem = lid / 6;
    const int y = rem % 64;
    const int z = rem / 64;
    const int koff = z * Khalf;
    gemm64_core(A + koff, Bt + koff, DD, Kstride, Khalf,
                Cpair + (size_t)z * MROWS * DD, DD, 0,
                y * 64, x * 128, As0, As1, Bs0, Bs1);
}

// ---------------------------------------------------------------------------
// Unified prep kernel (validated R20).
// ---------------------------------------------------------------------------
static __device__ __forceinline__ void tcvt_body(
    const float* __restrict__ in, u16* __restrict__ out,
    int K, int N, int bx, int by)
{
    __shared__ float t[32][33];
    const int n0 = bx * 32, k0 = by * 32;
    const int tx = threadIdx.x & 31, ty = threadIdx.x >> 5;
#pragma unroll
    for (int j = 0; j < 4; ++j)
        t[ty + j * 8][tx] = in[(size_t)(k0 + ty + j * 8) * N + n0 + tx];
    __syncthreads();
#pragma unroll
    for (int j = 0; j < 4; ++j)
        out[(size_t)(n0 + ty + j * 8) * K + k0 + tx] = f2bf(t[tx][ty + j * 8]);
}

__global__ __launch_bounds__(256) void prep_all(
    const float* __restrict__ x, const float* __restrict__ key_enc,
    const float* __restrict__ value_enc,
    u16* __restrict__ BFx, u16* __restrict__ BFK, u16* __restrict__ BFV,
    const float* __restrict__ wq_m, const float* __restrict__ wk_m,
    const float* __restrict__ wv_m, const float* __restrict__ wq_c,
    const float* __restrict__ wk_c, const float* __restrict__ wv_c,
    u16* __restrict__ Wm6,
    const float* __restrict__ wom, const float* __restrict__ woc,
    const float* __restrict__ w1, const float* __restrict__ w2,
    u16* __restrict__ womt, u16* __restrict__ woct,
    u16* __restrict__ w1t, u16* __restrict__ w2t)
{
    const int fid = (int)blockIdx.x;
    const int tid = threadIdx.x;
    if (fid < 9216) {
        const int z = fid / 3072;
        const float* s = (z == 0) ? x : (z == 1) ? key_enc : value_enc;
        u16* d = (z == 0) ? BFx : (z == 1) ? BFK : BFV;
        const int i = (fid % 3072) * 256 + tid;
        float4 v = ((const float4*)s)[i];
        ushort4 o;
        o.x = f2bf(v.x); o.y = f2bf(v.y); o.z = f2bf(v.z); o.w = f2bf(v.w);
        ((ushort4*)d)[i] = o;
    } else if (fid < 12672) {
        const int l = fid - 9216;
        const int z = l / 48;
        const int r = l % 48;
        const int wi = z / 12, head = z % 12;
        const float* wsel = (wi == 0) ? wq_m : (wi == 1) ? wk_m :
                            (wi == 2) ? wv_m : (wi == 3) ? wq_c :
                            (wi == 4) ? wk_c : wv_c;
        const float* ib = wsel + (size_t)head * DD * DHD;
        u16* ob = Wm6 + (size_t)wi * WPC + (size_t)head * DHD * DD;
        __shared__ float t[32][33];
        const int n0 = (r % 2) * 32, k0 = (r / 2) * 32;
        const int tx = tid & 31, ty = tid >> 5;
#pragma unroll
        for (int j = 0; j < 4; ++j)
            t[ty + j * 8][tx] = ib[(size_t)(k0 + ty + j * 8) * DHD + n0 + tx];
        __syncthreads();
#pragma unroll
        for (int j = 0; j < 4; ++j)
            ob[(size_t)(n0 + ty + j * 8) * DD + k0 + tx] = f2bf(t[tx][ty + j * 8]);
    } else {
        const int l = fid - 12672;
        if (l < 576) {
            tcvt_body(wom, womt, DD, DD, l % 24, l / 24);
        } else if (l < 1152) {
            const int m = l - 576;
            tcvt_body(woc, woct, DD, DD, m % 24, m / 24);
        } else if (l < 3456) {
            const int m = l - 1152;
            tcvt_body(w1, w1t, DD, FF, m % 96, m / 96);
        } else {
            const int m = l - 3456;
            tcvt_body(w2, w2t, FF, DD, m % 24, m / 24);
        }
    }
}

// ---------------------------------------------------------------------------
// MFMA flash attention (R24/R26 config, R29 balanced QBTAB) + even-qt
// diagonal half-tile skip: for even qt the diag tile's keys 64-127 are all
// > every qrow -> fi 4-7 and PV kk 2-3 are exact zeros; skip them (8 QK +
// 8 PV MFMAs + 16 exp2/thread saved on 8 of 16 q-tiles, bit-identical).
// ---------------------------------------------------------------------------
#define KAST 72
#define PAST 136
#define CSC 0.18033688011112042f   // 0.125 * log2(e)
__global__ __launch_bounds__(256) void attn_mfma_kernel(
    const u16* __restrict__ Q, int ldq,
    const u16* __restrict__ K, const u16* __restrict__ V, int ldkv,
    const int* __restrict__ kmask, u16* __restrict__ O, int causal)
{
    const int lid = xcd_swz(16 * BB * HH);
    int qt, bh;
    if (causal) {
        const int x   = lid / 96;
        const int l   = lid % 96;
        const int t   = l >> 5;
        const int r   = l & 31;
        const int r16 = r & 15;
        const int rh  = r >> 4;
        const unsigned int e = QBTAB[r16 * 3 + t];
        qt = (int)(e & 15u);
        bh = x * 6 + (int)(e >> 4) * 2 + rh;
    } else {
        qt = lid % 16;
        bh = lid / 16;
    }
    const int b  = bh / HH;
    const int h  = bh % HH;
    const int tid  = threadIdx.x;
    const int lane = tid & 63;
    const int w    = tid >> 6;
    const int lr = lane & 15;
    const int lg = lane >> 4;

    __shared__ u16 Ks[128 * KAST];
    __shared__ u16 Ps[64 * PAST];
    __shared__ u16 Vt[64 * PAST];

    const int row0 = qt * 64;
    const int q0w  = row0 + w * 16;

    bf16x8 qf[2];
    {
        const u16* qp = Q + (size_t)(b * SS + q0w + lr) * ldq + h * DHD + lg * 8;
        qf[0] = __builtin_bit_cast(bf16x8, *(const u16x8*)(qp));
        qf[1] = __builtin_bit_cast(bf16x8, *(const u16x8*)(qp + 32));
    }

    const int sr  = tid >> 1;
    const int scb = (tid & 1) * 32;
    const int vk  = tid >> 1;
    const int vdb = (tid & 1) * 32;
    const int k6  = vk & 63;
    const int vcol = ((vk >> 6) << 6) | ((k6 & 15) << 2) | (k6 >> 4);

    f32x4 acc[4] = {};
    float lsum[4] = {0.0f, 0.0f, 0.0f, 0.0f};

    const int nkt = causal ? ((qt + 2) >> 1) : 8;

    u16x8 kr0, kr1, kr2, kr3, vr0, vr1, vr2, vr3;
    {
        const u16* kp = K + (size_t)(b * SS + sr) * ldkv + h * DHD + scb;
        kr0 = *(const u16x8*)(kp);
        kr1 = *(const u16x8*)(kp + 8);
        kr2 = *(const u16x8*)(kp + 16);
        kr3 = *(const u16x8*)(kp + 24);
        const u16* vp = V + (size_t)(b * SS + vk) * ldkv + h * DHD + vdb;
        vr0 = *(const u16x8*)(vp);
        vr1 = *(const u16x8*)(vp + 8);
        vr2 = *(const u16x8*)(vp + 16);
        vr3 = *(const u16x8*)(vp + 24);
    }

    for (int kt = 0; kt < nkt; ++kt) {
        const int kcol0 = kt * 128;
        if (kt) __syncthreads();

        *(u16x8*)(&Ks[sr * KAST + scb])      = kr0;
        *(u16x8*)(&Ks[sr * KAST + scb + 8])  = kr1;
        *(u16x8*)(&Ks[sr * KAST + scb + 16]) = kr2;
        *(u16x8*)(&Ks[sr * KAST + scb + 24]) = kr3;
#pragma unroll
        for (int j = 0; j < 8; ++j) Vt[(vdb + j) * PAST + vcol]      = vr0[j];
#pragma unroll
        for (int j = 0; j < 8; ++j) Vt[(vdb + 8 + j) * PAST + vcol]  = vr1[j];
#pragma unroll
        for (int j = 0; j < 8; ++j) Vt[(vdb + 16 + j) * PAST + vcol] = vr2[j];
#pragma unroll
        for (int j = 0; j < 8; ++j) Vt[(vdb + 24 + j) * PAST + vcol] = vr3[j];
        __syncthreads();

        if (kt + 1 < nkt) {
            const int kn = kcol0 + 128;
            const u16* kp = K + (size_t)(b * SS + kn + sr) * ldkv + h * DHD + scb;
            kr0 = *(const u16x8*)(kp);
            kr1 = *(const u16x8*)(kp + 8);
            kr2 = *(const u16x8*)(kp + 16);
            kr3 = *(const u16x8*)(kp + 24);
            const u16* vp = V + (size_t)(b * SS + kn + vk) * ldkv + h * DHD + vdb;
            vr0 = *(const u16x8*)(vp);
            vr1 = *(const u16x8*)(vp + 8);
            vr2 = *(const u16x8*)(vp + 16);
            vr3 = *(const u16x8*)(vp + 24);
        }

        const bool diag = (causal != 0) && (kt == nkt - 1);
        const bool halfDiag = diag && !(qt & 1);   // keys 64-127 all masked

        // QK^T: key-groups fi (skip upper half when halfDiag)
        f32x4 s[8] = {};
        __builtin_amdgcn_s_setprio(1);
#pragma unroll
        for (int fi = 0; fi < 4; ++fi) {
            bf16x8 kf0 = __builtin_bit_cast(bf16x8, *(const u16x8*)(&Ks[(fi * 16 + lr) * KAST + lg * 8]));
            bf16x8 kf1 = __builtin_bit_cast(bf16x8, *(const u16x8*)(&Ks[(fi * 16 + lr) * KAST + 32 + lg * 8]));
            s[fi] = __builtin_amdgcn_mfma_f32_16x16x32_bf16(qf[0], kf0, s[fi], 0, 0, 0);
            s[fi] = __builtin_amdgcn_mfma_f32_16x16x32_bf16(qf[1], kf1, s[fi], 0, 0, 0);
        }
        if (!halfDiag) {
#pragma unroll
            for (int fi = 4; fi < 8; ++fi) {
                bf16x8 kf0 = __builtin_bit_cast(bf16x8, *(const u16x8*)(&Ks[(fi * 16 + lr) * KAST + lg * 8]));
                bf16x8 kf1 = __builtin_bit_cast(bf16x8, *(const u16x8*)(&Ks[(fi * 16 + lr) * KAST + 32 + lg * 8]));
                s[fi] = __builtin_amdgcn_mfma_f32_16x16x32_bf16(qf[0], kf0, s[fi], 0, 0, 0);
                s[fi] = __builtin_amdgcn_mfma_f32_16x16x32_bf16(qf[1], kf1, s[fi], 0, 0, 0);
            }
        }
        __builtin_amdgcn_s_setprio(0);

        float biasf[8];
#pragma unroll
        for (int fi = 0; fi < 8; ++fi)
            biasf[fi] = kmask[b * SS + kcol0 + fi * 16 + lr] ? 0.0f : -INFINITY;

#pragma unroll
        for (int r = 0; r < 4; ++r) {
            const int qrow = q0w + lg * 4 + r;
            const int prow = (w * 16 + lg * 4 + r) * PAST;
            u16x4 pk0, pk1;
            float rs = 0.0f;
#pragma unroll
            for (int fi = 0; fi < 4; ++fi) {
                float v = fmaf(s[fi][r], CSC, biasf[fi]);
                if (diag) {
                    const int key = kcol0 + fi * 16 + lr;
                    v = (key <= qrow) ? v : -INFINITY;
                }
                const float pv = exp2f(v);
                pk0[fi] = f2bf(pv);
                rs += pv;
            }
            if (halfDiag) {
                pk1[0] = 0; pk1[1] = 0; pk1[2] = 0; pk1[3] = 0;
            } else {
#pragma unroll
                for (int fi = 4; fi < 8; ++fi) {
                    float v = fmaf(s[fi][r], CSC, biasf[fi]);
                    if (diag) {
                        const int key = kcol0 + fi * 16 + lr;
                        v = (key <= qrow) ? v : -INFINITY;
                    }
                    const float pv = exp2f(v);
                    pk1[fi - 4] = f2bf(pv);
                    rs += pv;
                }
            }
            lsum[r] += rs;
            *(u16x4*)(&Ps[prow + lr * 4])      = pk0;
            *(u16x4*)(&Ps[prow + 64 + lr * 4]) = pk1;
        }

        // PV (skip kk 2-3 when halfDiag: those P columns are exact zeros)
        __builtin_amdgcn_s_setprio(1);
        const int nkk = halfDiag ? 2 : 4;
        for (int kk = 0; kk < nkk; ++kk) {
            bf16x8 pf = __builtin_bit_cast(bf16x8, *(const u16x8*)(&Ps[(w * 16 + lr) * PAST + kk * 32 + lg * 8]));
#pragma unroll
            for (int di = 0; di < 4; ++di) {
                bf16x8 vf = __builtin_bit_cast(bf16x8, *(const u16x8*)(&Vt[(di * 16 + lr) * PAST + kk * 32 + lg * 8]));
                acc[di] = __builtin_amdgcn_mfma_f32_16x16x32_bf16(pf, vf, acc[di], 0, 0, 0);
            }
        }
        __builtin_amdgcn_s_setprio(0);
    }

#pragma unroll
    for (int r = 0; r < 4; ++r) {
        float l = lsum[r];
        l += __shfl_xor(l, 1);
        l += __shfl_xor(l, 2);
        l += __shfl_xor(l, 4);
        l += __shfl_xor(l, 8);
        const float inv = (l > 0.0f) ? (1.0f / l) : 0.0f;
        const size_t orow = (size_t)(b * SS + q0w + lg * 4 + r) * DD + h * DHD;
#pragma unroll
        for (int di = 0; di < 4; ++di)
            O[orow + di * 16 + lr] = f2bf(acc[di][r] * inv);
    }
}

// ---------------------------------------------------------------------------
// Generic LayerNorm over (P0 + P1 [+ bias] [+ residf32 | residb16]) ->
// optional fp32 and/or bf16 outputs.
// ---------------------------------------------------------------------------
__global__ __launch_bounds__(256) void ln_red_gen(
    const u16* __restrict__ P0, const u16* __restrict__ P1,
    const float* __restrict__ bias,
    const float* __restrict__ residf, const u16* __restrict__ residb,
    const float* __restrict__ gma, const float* __restrict__ bta,
    float* __restrict__ Yf, u16* __restrict__ Ybf)
{
    const int row = blockIdx.x;
    const int tid = threadIdx.x;
    const size_t base = (size_t)row * DD;

    float v[3];
#pragma unroll
    for (int j = 0; j < 3; ++j) {
        const int i = tid + j * 256;
        float t = bf2f(P0[base + i]) + bf2f(P1[base + i]);
        if (bias)   t += bias[i];
        if (residf) t += residf[base + i];
        if (residb) t += bf2f(residb[base + i]);
        v[j] = t;
    }

    __shared__ float sd[256];
    sd[tid] = v[0] + v[1] + v[2];
    __syncthreads();
    for (int off = 128; off > 0; off >>= 1) {
        if (tid < off) sd[tid] += sd[tid + off];
        __syncthreads();
    }
    const float mean = sd[0] * (1.0f / 768.0f);
    __syncthreads();

    float q[3];
#pragma unroll
    for (int j = 0; j < 3; ++j) q[j] = v[j] - mean;
    sd[tid] = q[0] * q[0] + q[1] * q[1] + q[2] * q[2];
    __syncthreads();
    for (int off = 128; off > 0; off >>= 1) {
        if (tid < off) sd[tid] += sd[tid + off];
        __syncthreads();
    }
    const float var = sd[0] * (1.0f / 768.0f);
    const float inv = rsqrtf(var + 1e-5f);

#pragma unroll
    for (int j = 0; j < 3; ++j) {
        const int i = tid + j * 256;
        const float y = q[j] * inv * gma[i] + bta[i];
        if (Yf)  Yf[base + i] = y;
        if (Ybf) Ybf[base + i] = f2bf(y);
    }
}

// ---------------------------------------------------------------------------
extern "C" void kernel_launch(void* const* d_in, const int* in_sizes, int n_in,
                              void* d_out, int out_size, void* d_ws, size_t ws_size,
                              hipStream_t stream)
{
    (void)in_sizes; (void)n_in; (void)out_size; (void)ws_size;

    const float* key_enc   = (const float*)d_in[0];
    const float* value_enc = (const float*)d_in[1];
    const float* x         = (const float*)d_in[2];
    const int*   src_mask  = (const int*)d_in[3];
    const int*   tgt_mask  = (const int*)d_in[4];
    const float* Wq_m = (const float*)d_in[5];
    const float* Wk_m = (const float*)d_in[6];
    const float* Wv_m = (const float*)d_in[7];
    const float* Wo_m = (const float*)d_in[8];
    const float* Wq_c = (const float*)d_in[9];
    const float* Wk_c = (const float*)d_in[10];
    const float* Wv_c = (const float*)d_in[11];
    const float* Wo_c = (const float*)d_in[12];
    const float* ln1_g = (const float*)d_in[13];
    const float* ln1_b = (const float*)d_in[14];
    const float* ln2_g = (const float*)d_in[15];
    const float* ln2_b = (const float*)d_in[16];
    const float* ln3_g = (const float*)d_in[17];
    const float* ln3_b = (const float*)d_in[18];
    const float* W1 = (const float*)d_in[19];
    const float* b1 = (const float*)d_in[20];
    const float* W2 = (const float*)d_in[21];
    const float* b2 = (const float*)d_in[22];

    float* out = (float*)d_out;

    // workspace layout
    const size_t ACT = (size_t)MROWS * DD;
    char* p = (char*)d_ws;
    u16* QKV  = (u16*)p;   p += 3 * ACT * 2;
    u16* BFx  = (u16*)p;   p += ACT * 2;
    u16* BFK  = (u16*)p;   p += ACT * 2;
    u16* BFV  = (u16*)p;   p += ACT * 2;
    u16* BF1a = (u16*)p;   p += ACT * 2;
    u16* BF1h = (u16*)p;   p += ACT * 2;
    u16* T2bf = (u16*)p;   p += ACT * 2;           // spare
    u16* SKKV = (u16*)p;   p += 2 * ACT * 2;       // cross-KV | MLP2 partials
    u16* Wm6  = (u16*)p;   p += 6 * (size_t)WPC * 2;
    u16* Wom_t = (u16*)p;  p += (size_t)WPC * 2;
    u16* Woc_t = (u16*)p;  p += (size_t)WPC * 2;
    u16* W1t  = (u16*)p;   p += (size_t)DD * FF * 2;
    u16* W2t  = (u16*)p;   p += (size_t)DD * FF * 2;
    u16* MID  = QKV;       // [4096][3072] aliases QKV+BFx (dead by MLP)
    u16* KVc  = SKKV;      // cross K|V (dead by MLP2)
    u16* SKa  = QKV;       // Wo split-K partial 0 (QKV dead after each attn)
    u16* SKb  = QKV + ACT; // Wo split-K partial 1
    u16* SK0  = SKKV;      // MLP2 partial 0
    u16* SK1  = SKKV + ACT;
    (void)T2bf;

    const dim3 blk(256);

    // Unified prep (1 dispatch)
    prep_all<<<dim3(18432), blk, 0, stream>>>(
        x, key_enc, value_enc, BFx, BFK, BFV,
        Wq_m, Wk_m, Wv_m, Wq_c, Wk_c, Wv_c, Wm6,
        Wo_m, Wo_c, W1, W2, Wom_t, Woc_t, W1t, W2t);

    gemm128_proj<<<dim3(960), blk, 0, stream>>>(BFx, BFK, BFV, Wm6, QKV, KVc);

    // Self-attention; Wo_m split-K into QKV region (dead); fused ln1.
    attn_mfma_kernel<<<dim3(768), blk, 0, stream>>>(
        QKV, 3 * DD, QKV + DD, QKV + 2 * DD, 3 * DD, tgt_mask, BF1a, 1);
    gemm64_sk<<<dim3(768), blk, 0, stream>>>(BF1a, Wom_t, DD, DD / 2, SKa);
    ln_red_gen<<<MROWS, blk, 0, stream>>>(SKa, SKb, nullptr, x, nullptr,
                                          ln1_g, ln1_b, nullptr, BF1h);

    // Cross-attention: Q proj -> attn -> Wo_c split-K -> fused ln2.
    gemm64<<<dim3(384), blk, 0, stream>>>(BF1h, Wm6 + 3 * WPC, QKV, 3 * DD);
    attn_mfma_kernel<<<dim3(768), blk, 0, stream>>>(
        QKV, 3 * DD, KVc, KVc + DD, 2 * DD, src_mask, BF1a, 0);
    gemm64_sk<<<dim3(768), blk, 0, stream>>>(BF1a, Woc_t, DD, DD / 2, SKa);
    ln_red_gen<<<MROWS, blk, 0, stream>>>(SKa, SKb, nullptr, nullptr, BF1h,
                                          ln2_g, ln2_b, nullptr, BF1h);

    // MLP
    gemm128_mlp1<<<dim3(768), blk, 0, stream>>>(BF1h, W1t, b1, MID);
    gemm64_sk<<<dim3(768), blk, 0, stream>>>(MID, W2t, FF, FF / 2, SK0);
    ln_red_gen<<<MROWS, blk, 0, stream>>>(SK0, SK1, b2, nullptr, BF1h,
                                          ln3_g, ln3_b, out, nullptr);
}

// Round 34
// 243.955 us; speedup vs baseline: 1.0807x; 1.0807x over previous
//
#include <hip/hip_runtime.h>
#include <math.h>

// Problem constants
#define BB 4
#define SS 1024
#define DD 768
#define HH 12
#define DHD 64
#define MROWS 4096
#define FF 3072
#define WPC (DD * DD)

typedef unsigned short u16;
typedef float f32x4 __attribute__((ext_vector_type(4)));
typedef __bf16 bf16x8 __attribute__((ext_vector_type(8)));
typedef unsigned short u16x8 __attribute__((ext_vector_type(8)));
typedef unsigned short u16x4 __attribute__((ext_vector_type(4)));

static __device__ __forceinline__ float bf2f(u16 u) {
    union { unsigned int i; float f; } c; c.i = ((unsigned int)u) << 16; return c.f;
}
static __device__ __forceinline__ u16 f2bf(float f) {
    return __builtin_bit_cast(u16, static_cast<__bf16>(f));
}
// XCD-chunked swizzle: flat grid, total % 8 == 0.
static __device__ __forceinline__ int xcd_swz(int total) {
    const int bid = (int)blockIdx.x;
    return (bid & 7) * (total >> 3) + (bid >> 3);
}
// Async global->LDS, 16B per lane.
static __device__ __forceinline__ void gload16(const u16* g, u16* l) {
    __builtin_amdgcn_global_load_lds(
        (const __attribute__((address_space(1))) void*)g,
        (__attribute__((address_space(3))) void*)l, 16, 0, 0);
}
// GELU tanh-form via sigmoid: x*sigmoid(1.5958(x+0.044715x^3)).
// exp2-domain, hw rcp. Max abs error vs exact erf-GELU ~3e-4.
static __device__ __forceinline__ float gelu_f(float x) {
    const float x2 = x * x;
    const float t  = x * fmaf(x2, -0.10294437f, -2.30220800f);
    return x * __builtin_amdgcn_rcpf(1.0f + exp2f(t));
}

// Balanced causal q-tile map (R29-validated). Co-resident blocks on a CU are
// lids {L, L+32, L+64}; entry = qt | (B<<4); each triple sums nkt 13-14.
// XCD L2 locality preserved (R30 lesson: dynamic assignment destroys it;
// R33 lesson: divergent diag work-skip costs VGPR 80->92 / occupancy -> net
// regression — keep the inner loop branch-free and statically unrolled).
static __device__ const unsigned char QBTAB[48] = {
    15,  7,  3,
    14,  6,  2,
    31, 23,  1,
    30, 22,  0,
    47,  5, 19,
    46,  4, 18,
    13, 11, 17,
    12, 10, 16,
    29,  9, 35,
    28,  8, 34,
    45, 25, 33,
    44, 24, 32,
    27, 41, 21,
    26, 40, 20,
    43, 39, 37,
    42, 38, 36,
};

// ---------------------------------------------------------------------------
// 128x128-tile bf16 MFMA GEMM core, async staging, BK=64 dual k-half buffers.
// (BK=128 would need 64KB LDS -> occupancy loss; R32 falsified it for gemm64
// too: 49KB dropped 6->3 blocks/CU and erased the barrier savings.)
// ---------------------------------------------------------------------------
static __device__ __forceinline__ void gemm128_core(
    const u16* __restrict__ A, const u16* __restrict__ Bt,
    int K,
    const float* __restrict__ bias, int do_gelu,
    u16* __restrict__ Cbf, int ldcbf, int cboff,
    int row0, int col0, u16* As0, u16* As1, u16* Bs0, u16* Bs1)
{
    const int tid  = threadIdx.x;
    const int lane = tid & 63;
    const int w    = tid >> 6;
    const int wm = (w >> 1) * 64;
    const int wn = (w & 1) * 64;

    const u16* Ap = A  + (size_t)(row0 + w * 32 + (lane >> 2)) * K + (lane & 3) * 8;
    const u16* Bp = Bt + (size_t)(col0 + w * 32 + (lane >> 2)) * K + (lane & 3) * 8;
    const int woff = (w * 32) * 32;

    const int fr = lane & 15;
    const int fk = (lane >> 4) * 8;
    const int afo = (wm + fr) * 32 + fk;
    const int bfo = (wn + fr) * 32 + fk;

    f32x4 acc[4][4] = {};

    for (int k0 = 0; k0 < K; k0 += 64) {
        if (k0) __syncthreads();
        gload16(Ap + k0,               As0 + woff);
        gload16(Ap + k0 + 16 * K,      As0 + woff + 16 * 32);
        gload16(Ap + k0 + 32,          As1 + woff);
        gload16(Ap + k0 + 32 + 16 * K, As1 + woff + 16 * 32);
        gload16(Bp + k0,               Bs0 + woff);
        gload16(Bp + k0 + 16 * K,      Bs0 + woff + 16 * 32);
        gload16(Bp + k0 + 32,          Bs1 + woff);
        gload16(Bp + k0 + 32 + 16 * K, Bs1 + woff + 16 * 32);
        __syncthreads();

        {
            bf16x8 af[4], bfv[4];
#pragma unroll
            for (int mi = 0; mi < 4; ++mi)
                af[mi] = __builtin_bit_cast(bf16x8,
                    *(const u16x8*)(As0 + afo + mi * 16 * 32));
#pragma unroll
            for (int ni = 0; ni < 4; ++ni)
                bfv[ni] = __builtin_bit_cast(bf16x8,
                    *(const u16x8*)(Bs0 + bfo + ni * 16 * 32));
#pragma unroll
            for (int mi = 0; mi < 4; ++mi)
#pragma unroll
                for (int ni = 0; ni < 4; ++ni)
                    acc[mi][ni] = __builtin_amdgcn_mfma_f32_16x16x32_bf16(
                        af[mi], bfv[ni], acc[mi][ni], 0, 0, 0);
        }
        {
            bf16x8 af[4], bfv[4];
#pragma unroll
            for (int mi = 0; mi < 4; ++mi)
                af[mi] = __builtin_bit_cast(bf16x8,
                    *(const u16x8*)(As1 + afo + mi * 16 * 32));
#pragma unroll
            for (int ni = 0; ni < 4; ++ni)
                bfv[ni] = __builtin_bit_cast(bf16x8,
                    *(const u16x8*)(Bs1 + bfo + ni * 16 * 32));
#pragma unroll
            for (int mi = 0; mi < 4; ++mi)
#pragma unroll
                for (int ni = 0; ni < 4; ++ni)
                    acc[mi][ni] = __builtin_amdgcn_mfma_f32_16x16x32_bf16(
                        af[mi], bfv[ni], acc[mi][ni], 0, 0, 0);
        }
    }

    const int orow0 = row0 + wm + (lane >> 4) * 4;
    const int ocol0 = col0 + wn + fr;
#pragma unroll
    for (int mi = 0; mi < 4; ++mi) {
#pragma unroll
        for (int ni = 0; ni < 4; ++ni) {
            const int col = ocol0 + ni * 16;
            const float bv = bias ? bias[col] : 0.0f;
#pragma unroll
            for (int r = 0; r < 4; ++r) {
                const int row = orow0 + mi * 16 + r;
                float v = acc[mi][ni][r] + bv;
                if (do_gelu) v = gelu_f(v);
                Cbf[(size_t)row * ldcbf + cboff + col] = f2bf(v);
            }
        }
    }
}

// MLP1: flat 768-block grid, XCD-swizzled.
__global__ __launch_bounds__(256) void gemm128_mlp1(
    const u16* __restrict__ A, const u16* __restrict__ Bt,
    const float* __restrict__ bias, u16* __restrict__ Cbf)
{
    __shared__ u16 As0[128 * 32];
    __shared__ u16 As1[128 * 32];
    __shared__ u16 Bs0[128 * 32];
    __shared__ u16 Bs1[128 * 32];
    const int lid = xcd_swz(24 * 32);
    gemm128_core(A, Bt, DD, bias, 1, Cbf, FF, 0,
                 (lid / 24) * 128, (lid % 24) * 128, As0, As1, Bs0, Bs1);
}

// Batched independent projections, flat 960-block grid, XCD-swizzled.
__global__ __launch_bounds__(256) void gemm128_proj(
    const u16* __restrict__ BFx, const u16* __restrict__ BFK,
    const u16* __restrict__ BFV, const u16* __restrict__ Wm6,
    u16* __restrict__ QKV, u16* __restrict__ KVc)
{
    __shared__ u16 As0[128 * 32];
    __shared__ u16 As1[128 * 32];
    __shared__ u16 Bs0[128 * 32];
    __shared__ u16 Bs1[128 * 32];
    const int fid = xcd_swz(960);
    const u16* A; const u16* B; u16* C; int ldc, coff, row0, col0;
    if (fid < 576) {
        A = BFx; B = Wm6; C = QKV; ldc = 3 * DD; coff = 0;
        row0 = (fid / 18) * 128; col0 = (fid % 18) * 128;
    } else if (fid < 768) {
        const int l = fid - 576;
        A = BFK; B = Wm6 + 4 * WPC; C = KVc; ldc = 2 * DD; coff = 0;
        row0 = (l / 6) * 128; col0 = (l % 6) * 128;
    } else {
        const int l = fid - 768;
        A = BFV; B = Wm6 + 5 * WPC; C = KVc; ldc = 2 * DD; coff = DD;
        row0 = (l / 6) * 128; col0 = (l % 6) * 128;
    }
    gemm128_core(A, B, DD, nullptr, 0, C, ldc, coff, row0, col0,
                 As0, As1, Bs0, Bs1);
}

// ---------------------------------------------------------------------------
// 64x128-tile GEMM core, async staging, BK=64 dual k-half buffers
// (R31-exact; R32's BK=128 quad-buffer regressed via occupancy 6->3).
// ---------------------------------------------------------------------------
static __device__ __forceinline__ void gemm64_core(
    const u16* __restrict__ A, const u16* __restrict__ Bt,
    int N, int Kstride, int Klen,
    u16* __restrict__ Cbf, int ldcbf, int cboff,
    int row0, int col0, u16* As0, u16* As1, u16* Bs0, u16* Bs1)
{
    const int tid  = threadIdx.x;
    const int lane = tid & 63;
    const int w    = tid >> 6;
    const int wm = (w >> 1) * 32;
    const int wn = (w & 1) * 64;

    const u16* Ap = A  + (size_t)(row0 + w * 16 + (lane >> 2)) * Kstride + (lane & 3) * 8;
    const u16* Bp = Bt + (size_t)(col0 + w * 32 + (lane >> 2)) * Kstride + (lane & 3) * 8;
    const int aoff = (w * 16) * 32;
    const int boff = (w * 32) * 32;

    const int fr = lane & 15;
    const int fk = (lane >> 4) * 8;
    const int afo = (wm + fr) * 32 + fk;
    const int bfo = (wn + fr) * 32 + fk;

    f32x4 acc[2][4] = {};

    for (int k0 = 0; k0 < Klen; k0 += 64) {
        if (k0) __syncthreads();
        gload16(Ap + k0,                     As0 + aoff);
        gload16(Ap + k0 + 32,                As1 + aoff);
        gload16(Bp + k0,                     Bs0 + boff);
        gload16(Bp + k0 + 16 * Kstride,      Bs0 + boff + 16 * 32);
        gload16(Bp + k0 + 32,                Bs1 + boff);
        gload16(Bp + k0 + 32 + 16 * Kstride, Bs1 + boff + 16 * 32);
        __syncthreads();

        {
            bf16x8 af[2], bfv[4];
#pragma unroll
            for (int mi = 0; mi < 2; ++mi)
                af[mi] = __builtin_bit_cast(bf16x8,
                    *(const u16x8*)(As0 + afo + mi * 16 * 32));
#pragma unroll
            for (int ni = 0; ni < 4; ++ni)
                bfv[ni] = __builtin_bit_cast(bf16x8,
                    *(const u16x8*)(Bs0 + bfo + ni * 16 * 32));
#pragma unroll
            for (int mi = 0; mi < 2; ++mi)
#pragma unroll
                for (int ni = 0; ni < 4; ++ni)
                    acc[mi][ni] = __builtin_amdgcn_mfma_f32_16x16x32_bf16(
                        af[mi], bfv[ni], acc[mi][ni], 0, 0, 0);
        }
        {
            bf16x8 af[2], bfv[4];
#pragma unroll
            for (int mi = 0; mi < 2; ++mi)
                af[mi] = __builtin_bit_cast(bf16x8,
                    *(const u16x8*)(As1 + afo + mi * 16 * 32));
#pragma unroll
            for (int ni = 0; ni < 4; ++ni)
                bfv[ni] = __builtin_bit_cast(bf16x8,
                    *(const u16x8*)(Bs1 + bfo + ni * 16 * 32));
#pragma unroll
            for (int mi = 0; mi < 2; ++mi)
#pragma unroll
                for (int ni = 0; ni < 4; ++ni)
                    acc[mi][ni] = __builtin_amdgcn_mfma_f32_16x16x32_bf16(
                        af[mi], bfv[ni], acc[mi][ni], 0, 0, 0);
        }
    }

    const int orow0 = row0 + wm + (lane >> 4) * 4;
    const int ocol0 = col0 + wn + fr;
#pragma unroll
    for (int mi = 0; mi < 2; ++mi) {
#pragma unroll
        for (int ni = 0; ni < 4; ++ni) {
            const int col = ocol0 + ni * 16;
#pragma unroll
            for (int r = 0; r < 4; ++r) {
                const int row = orow0 + mi * 16 + r;
                Cbf[(size_t)row * ldcbf + cboff + col] = f2bf(acc[mi][ni][r]);
            }
        }
    }
}

// Cross-Q projection: N=K=768, output strided into QKV. 384 blocks.
__global__ __launch_bounds__(256) void gemm64(
    const u16* __restrict__ A, const u16* __restrict__ Bt,
    u16* __restrict__ Cbf, int ldcbf)
{
    __shared__ u16 As0[64 * 32];
    __shared__ u16 As1[64 * 32];
    __shared__ u16 Bs0[128 * 32];
    __shared__ u16 Bs1[128 * 32];
    const int lid = xcd_swz(6 * 64);
    gemm64_core(A, Bt, DD, DD, DD, Cbf, ldcbf, 0,
                (lid / 6) * 64, (lid % 6) * 128, As0, As1, Bs0, Bs1);
}

// Split-K x2 GEMM (Wo / MLP2): 768 blocks; bf16 partials to Cpair.
__global__ __launch_bounds__(256) void gemm64_sk(
    const u16* __restrict__ A, const u16* __restrict__ Bt,
    int Kstride, int Khalf, u16* __restrict__ Cpair)
{
    __shared__ u16 As0[64 * 32];
    __shared__ u16 As1[64 * 32];
    __shared__ u16 Bs0[128 * 32];
    __shared__ u16 Bs1[128 * 32];
    const int lid = xcd_swz(6 * 64 * 2);
    const int x = lid % 6;
    const int rem = lid / 6;
    const int y = rem % 64;
    const int z = rem / 64;
    const int koff = z * Khalf;
    gemm64_core(A + koff, Bt + koff, DD, Kstride, Khalf,
                Cpair + (size_t)z * MROWS * DD, DD, 0,
                y * 64, x * 128, As0, As1, Bs0, Bs1);
}

// ---------------------------------------------------------------------------
// Unified prep kernel (validated R20).
// ---------------------------------------------------------------------------
static __device__ __forceinline__ void tcvt_body(
    const float* __restrict__ in, u16* __restrict__ out,
    int K, int N, int bx, int by)
{
    __shared__ float t[32][33];
    const int n0 = bx * 32, k0 = by * 32;
    const int tx = threadIdx.x & 31, ty = threadIdx.x >> 5;
#pragma unroll
    for (int j = 0; j < 4; ++j)
        t[ty + j * 8][tx] = in[(size_t)(k0 + ty + j * 8) * N + n0 + tx];
    __syncthreads();
#pragma unroll
    for (int j = 0; j < 4; ++j)
        out[(size_t)(n0 + ty + j * 8) * K + k0 + tx] = f2bf(t[tx][ty + j * 8]);
}

__global__ __launch_bounds__(256) void prep_all(
    const float* __restrict__ x, const float* __restrict__ key_enc,
    const float* __restrict__ value_enc,
    u16* __restrict__ BFx, u16* __restrict__ BFK, u16* __restrict__ BFV,
    const float* __restrict__ wq_m, const float* __restrict__ wk_m,
    const float* __restrict__ wv_m, const float* __restrict__ wq_c,
    const float* __restrict__ wk_c, const float* __restrict__ wv_c,
    u16* __restrict__ Wm6,
    const float* __restrict__ wom, const float* __restrict__ woc,
    const float* __restrict__ w1, const float* __restrict__ w2,
    u16* __restrict__ womt, u16* __restrict__ woct,
    u16* __restrict__ w1t, u16* __restrict__ w2t)
{
    const int fid = (int)blockIdx.x;
    const int tid = threadIdx.x;
    if (fid < 9216) {
        const int z = fid / 3072;
        const float* s = (z == 0) ? x : (z == 1) ? key_enc : value_enc;
        u16* d = (z == 0) ? BFx : (z == 1) ? BFK : BFV;
        const int i = (fid % 3072) * 256 + tid;
        float4 v = ((const float4*)s)[i];
        ushort4 o;
        o.x = f2bf(v.x); o.y = f2bf(v.y); o.z = f2bf(v.z); o.w = f2bf(v.w);
        ((ushort4*)d)[i] = o;
    } else if (fid < 12672) {
        const int l = fid - 9216;
        const int z = l / 48;
        const int r = l % 48;
        const int wi = z / 12, head = z % 12;
        const float* wsel = (wi == 0) ? wq_m : (wi == 1) ? wk_m :
                            (wi == 2) ? wv_m : (wi == 3) ? wq_c :
                            (wi == 4) ? wk_c : wv_c;
        const float* ib = wsel + (size_t)head * DD * DHD;
        u16* ob = Wm6 + (size_t)wi * WPC + (size_t)head * DHD * DD;
        __shared__ float t[32][33];
        const int n0 = (r % 2) * 32, k0 = (r / 2) * 32;
        const int tx = tid & 31, ty = tid >> 5;
#pragma unroll
        for (int j = 0; j < 4; ++j)
            t[ty + j * 8][tx] = ib[(size_t)(k0 + ty + j * 8) * DHD + n0 + tx];
        __syncthreads();
#pragma unroll
        for (int j = 0; j < 4; ++j)
            ob[(size_t)(n0 + ty + j * 8) * DD + k0 + tx] = f2bf(t[tx][ty + j * 8]);
    } else {
        const int l = fid - 12672;
        if (l < 576) {
            tcvt_body(wom, womt, DD, DD, l % 24, l / 24);
        } else if (l < 1152) {
            const int m = l - 576;
            tcvt_body(woc, woct, DD, DD, m % 24, m / 24);
        } else if (l < 3456) {
            const int m = l - 1152;
            tcvt_body(w1, w1t, DD, FF, m % 96, m / 96);
        } else {
            const int m = l - 3456;
            tcvt_body(w2, w2t, FF, DD, m % 24, m / 24);
        }
    }
}

// ---------------------------------------------------------------------------
// MFMA flash attention (R24/R26 config) with balanced causal q-tile map:
// co-resident block triples get nkt sums 13-14 instead of worst-case 24.
// (R30 lesson: dynamic/LPT assignment destroys XCD-L2 K/V locality.
//  R33 lesson: divergent even-qt diag skip costs VGPR/occupancy > work saved.)
// ---------------------------------------------------------------------------
#define KAST 72
#define PAST 136
#define CSC 0.18033688011112042f   // 0.125 * log2(e)
__global__ __launch_bounds__(256) void attn_mfma_kernel(
    const u16* __restrict__ Q, int ldq,
    const u16* __restrict__ K, const u16* __restrict__ V, int ldkv,
    const int* __restrict__ kmask, u16* __restrict__ O, int causal)
{
    const int lid = xcd_swz(16 * BB * HH);
    int qt, bh;
    if (causal) {
        // Balanced map: chunk x (6 bh), row r (16) x half rh, third t.
        const int x   = lid / 96;
        const int l   = lid % 96;
        const int t   = l >> 5;
        const int r   = l & 31;
        const int r16 = r & 15;
        const int rh  = r >> 4;
        const unsigned int e = QBTAB[r16 * 3 + t];
        qt = (int)(e & 15u);
        bh = x * 6 + (int)(e >> 4) * 2 + rh;
    } else {
        qt = lid % 16;
        bh = lid / 16;
    }
    const int b  = bh / HH;
    const int h  = bh % HH;
    const int tid  = threadIdx.x;
    const int lane = tid & 63;
    const int w    = tid >> 6;
    const int lr = lane & 15;
    const int lg = lane >> 4;

    __shared__ u16 Ks[128 * KAST];
    __shared__ u16 Ps[64 * PAST];
    __shared__ u16 Vt[64 * PAST];

    const int row0 = qt * 64;
    const int q0w  = row0 + w * 16;

    bf16x8 qf[2];
    {
        const u16* qp = Q + (size_t)(b * SS + q0w + lr) * ldq + h * DHD + lg * 8;
        qf[0] = __builtin_bit_cast(bf16x8, *(const u16x8*)(qp));
        qf[1] = __builtin_bit_cast(bf16x8, *(const u16x8*)(qp + 32));
    }

    const int sr  = tid >> 1;
    const int scb = (tid & 1) * 32;
    const int vk  = tid >> 1;
    const int vdb = (tid & 1) * 32;
    const int k6  = vk & 63;
    const int vcol = ((vk >> 6) << 6) | ((k6 & 15) << 2) | (k6 >> 4);

    f32x4 acc[4] = {};
    float lsum[4] = {0.0f, 0.0f, 0.0f, 0.0f};

    const int nkt = causal ? ((qt + 2) >> 1) : 8;

    u16x8 kr0, kr1, kr2, kr3, vr0, vr1, vr2, vr3;
    {
        const u16* kp = K + (size_t)(b * SS + sr) * ldkv + h * DHD + scb;
        kr0 = *(const u16x8*)(kp);
        kr1 = *(const u16x8*)(kp + 8);
        kr2 = *(const u16x8*)(kp + 16);
        kr3 = *(const u16x8*)(kp + 24);
        const u16* vp = V + (size_t)(b * SS + vk) * ldkv + h * DHD + vdb;
        vr0 = *(const u16x8*)(vp);
        vr1 = *(const u16x8*)(vp + 8);
        vr2 = *(const u16x8*)(vp + 16);
        vr3 = *(const u16x8*)(vp + 24);
    }

    for (int kt = 0; kt < nkt; ++kt) {
        const int kcol0 = kt * 128;
        if (kt) __syncthreads();

        *(u16x8*)(&Ks[sr * KAST + scb])      = kr0;
        *(u16x8*)(&Ks[sr * KAST + scb + 8])  = kr1;
        *(u16x8*)(&Ks[sr * KAST + scb + 16]) = kr2;
        *(u16x8*)(&Ks[sr * KAST + scb + 24]) = kr3;
#pragma unroll
        for (int j = 0; j < 8; ++j) Vt[(vdb + j) * PAST + vcol]      = vr0[j];
#pragma unroll
        for (int j = 0; j < 8; ++j) Vt[(vdb + 8 + j) * PAST + vcol]  = vr1[j];
#pragma unroll
        for (int j = 0; j < 8; ++j) Vt[(vdb + 16 + j) * PAST + vcol] = vr2[j];
#pragma unroll
        for (int j = 0; j < 8; ++j) Vt[(vdb + 24 + j) * PAST + vcol] = vr3[j];
        __syncthreads();

        if (kt + 1 < nkt) {
            const int kn = kcol0 + 128;
            const u16* kp = K + (size_t)(b * SS + kn + sr) * ldkv + h * DHD + scb;
            kr0 = *(const u16x8*)(kp);
            kr1 = *(const u16x8*)(kp + 8);
            kr2 = *(const u16x8*)(kp + 16);
            kr3 = *(const u16x8*)(kp + 24);
            const u16* vp = V + (size_t)(b * SS + kn + vk) * ldkv + h * DHD + vdb;
            vr0 = *(const u16x8*)(vp);
            vr1 = *(const u16x8*)(vp + 8);
            vr2 = *(const u16x8*)(vp + 16);
            vr3 = *(const u16x8*)(vp + 24);
        }

        // QK^T: 8 key-groups x 2 k-steps
        f32x4 s[8] = {};
        __builtin_amdgcn_s_setprio(1);
#pragma unroll
        for (int fi = 0; fi < 8; ++fi) {
            bf16x8 kf0 = __builtin_bit_cast(bf16x8, *(const u16x8*)(&Ks[(fi * 16 + lr) * KAST + lg * 8]));
            bf16x8 kf1 = __builtin_bit_cast(bf16x8, *(const u16x8*)(&Ks[(fi * 16 + lr) * KAST + 32 + lg * 8]));
            s[fi] = __builtin_amdgcn_mfma_f32_16x16x32_bf16(qf[0], kf0, s[fi], 0, 0, 0);
            s[fi] = __builtin_amdgcn_mfma_f32_16x16x32_bf16(qf[1], kf1, s[fi], 0, 0, 0);
        }
        __builtin_amdgcn_s_setprio(0);

        float biasf[8];
#pragma unroll
        for (int fi = 0; fi < 8; ++fi)
            biasf[fi] = kmask[b * SS + kcol0 + fi * 16 + lr] ? 0.0f : -INFINITY;
        const bool diag = (causal != 0) && (kt == nkt - 1);

#pragma unroll
        for (int r = 0; r < 4; ++r) {
            const int qrow = q0w + lg * 4 + r;
            const int prow = (w * 16 + lg * 4 + r) * PAST;
            u16x4 pk0, pk1;
            float rs = 0.0f;
#pragma unroll
            for (int fi = 0; fi < 8; ++fi) {
                float v = fmaf(s[fi][r], CSC, biasf[fi]);
                if (diag) {
                    const int key = kcol0 + fi * 16 + lr;
                    v = (key <= qrow) ? v : -INFINITY;
                }
                const float pv = exp2f(v);
                if (fi < 4) pk0[fi] = f2bf(pv); else pk1[fi - 4] = f2bf(pv);
                rs += pv;
            }
            lsum[r] += rs;
            *(u16x4*)(&Ps[prow + lr * 4])      = pk0;
            *(u16x4*)(&Ps[prow + 64 + lr * 4]) = pk1;
        }

        // PV
        __builtin_amdgcn_s_setprio(1);
#pragma unroll
        for (int kk = 0; kk < 4; ++kk) {
            bf16x8 pf = __builtin_bit_cast(bf16x8, *(const u16x8*)(&Ps[(w * 16 + lr) * PAST + kk * 32 + lg * 8]));
#pragma unroll
            for (int di = 0; di < 4; ++di) {
                bf16x8 vf = __builtin_bit_cast(bf16x8, *(const u16x8*)(&Vt[(di * 16 + lr) * PAST + kk * 32 + lg * 8]));
                acc[di] = __builtin_amdgcn_mfma_f32_16x16x32_bf16(pf, vf, acc[di], 0, 0, 0);
            }
        }
        __builtin_amdgcn_s_setprio(0);
    }

#pragma unroll
    for (int r = 0; r < 4; ++r) {
        float l = lsum[r];
        l += __shfl_xor(l, 1);
        l += __shfl_xor(l, 2);
        l += __shfl_xor(l, 4);
        l += __shfl_xor(l, 8);
        const float inv = (l > 0.0f) ? (1.0f / l) : 0.0f;
        const size_t orow = (size_t)(b * SS + q0w + lg * 4 + r) * DD + h * DHD;
#pragma unroll
        for (int di = 0; di < 4; ++di)
            O[orow + di * 16 + lr] = f2bf(acc[di][r] * inv);
    }
}

// ---------------------------------------------------------------------------
// Generic LayerNorm over (P0 + P1 [+ bias] [+ residf32 | residb16]) ->
// optional fp32 and/or bf16 outputs.
// ---------------------------------------------------------------------------
__global__ __launch_bounds__(256) void ln_red_gen(
    const u16* __restrict__ P0, const u16* __restrict__ P1,
    const float* __restrict__ bias,
    const float* __restrict__ residf, const u16* __restrict__ residb,
    const float* __restrict__ gma, const float* __restrict__ bta,
    float* __restrict__ Yf, u16* __restrict__ Ybf)
{
    const int row = blockIdx.x;
    const int tid = threadIdx.x;
    const size_t base = (size_t)row * DD;

    float v[3];
#pragma unroll
    for (int j = 0; j < 3; ++j) {
        const int i = tid + j * 256;
        float t = bf2f(P0[base + i]) + bf2f(P1[base + i]);
        if (bias)   t += bias[i];
        if (residf) t += residf[base + i];
        if (residb) t += bf2f(residb[base + i]);
        v[j] = t;
    }

    __shared__ float sd[256];
    sd[tid] = v[0] + v[1] + v[2];
    __syncthreads();
    for (int off = 128; off > 0; off >>= 1) {
        if (tid < off) sd[tid] += sd[tid + off];
        __syncthreads();
    }
    const float mean = sd[0] * (1.0f / 768.0f);
    __syncthreads();

    float q[3];
#pragma unroll
    for (int j = 0; j < 3; ++j) q[j] = v[j] - mean;
    sd[tid] = q[0] * q[0] + q[1] * q[1] + q[2] * q[2];
    __syncthreads();
    for (int off = 128; off > 0; off >>= 1) {
        if (tid < off) sd[tid] += sd[tid + off];
        __syncthreads();
    }
    const float var = sd[0] * (1.0f / 768.0f);
    const float inv = rsqrtf(var + 1e-5f);

#pragma unroll
    for (int j = 0; j < 3; ++j) {
        const int i = tid + j * 256;
        const float y = q[j] * inv * gma[i] + bta[i];
        if (Yf)  Yf[base + i] = y;
        if (Ybf) Ybf[base + i] = f2bf(y);
    }
}

// ---------------------------------------------------------------------------
extern "C" void kernel_launch(void* const* d_in, const int* in_sizes, int n_in,
                              void* d_out, int out_size, void* d_ws, size_t ws_size,
                              hipStream_t stream)
{
    (void)in_sizes; (void)n_in; (void)out_size; (void)ws_size;

    const float* key_enc   = (const float*)d_in[0];
    const float* value_enc = (const float*)d_in[1];
    const float* x         = (const float*)d_in[2];
    const int*   src_mask  = (const int*)d_in[3];
    const int*   tgt_mask  = (const int*)d_in[4];
    const float* Wq_m = (const float*)d_in[5];
    const float* Wk_m = (const float*)d_in[6];
    const float* Wv_m = (const float*)d_in[7];
    const float* Wo_m = (const float*)d_in[8];
    const float* Wq_c = (const float*)d_in[9];
    const float* Wk_c = (const float*)d_in[10];
    const float* Wv_c = (const float*)d_in[11];
    const float* Wo_c = (const float*)d_in[12];
    const float* ln1_g = (const float*)d_in[13];
    const float* ln1_b = (const float*)d_in[14];
    const float* ln2_g = (const float*)d_in[15];
    const float* ln2_b = (const float*)d_in[16];
    const float* ln3_g = (const float*)d_in[17];
    const float* ln3_b = (const float*)d_in[18];
    const float* W1 = (const float*)d_in[19];
    const float* b1 = (const float*)d_in[20];
    const float* W2 = (const float*)d_in[21];
    const float* b2 = (const float*)d_in[22];

    float* out = (float*)d_out;

    // workspace layout
    const size_t ACT = (size_t)MROWS * DD;
    char* p = (char*)d_ws;
    u16* QKV  = (u16*)p;   p += 3 * ACT * 2;
    u16* BFx  = (u16*)p;   p += ACT * 2;
    u16* BFK  = (u16*)p;   p += ACT * 2;
    u16* BFV  = (u16*)p;   p += ACT * 2;
    u16* BF1a = (u16*)p;   p += ACT * 2;
    u16* BF1h = (u16*)p;   p += ACT * 2;
    u16* T2bf = (u16*)p;   p += ACT * 2;           // spare
    u16* SKKV = (u16*)p;   p += 2 * ACT * 2;       // cross-KV | MLP2 partials
    u16* Wm6  = (u16*)p;   p += 6 * (size_t)WPC * 2;
    u16* Wom_t = (u16*)p;  p += (size_t)WPC * 2;
    u16* Woc_t = (u16*)p;  p += (size_t)WPC * 2;
    u16* W1t  = (u16*)p;   p += (size_t)DD * FF * 2;
    u16* W2t  = (u16*)p;   p += (size_t)DD * FF * 2;
    u16* MID  = QKV;       // [4096][3072] aliases QKV+BFx (dead by MLP)
    u16* KVc  = SKKV;      // cross K|V (dead by MLP2)
    u16* SKa  = QKV;       // Wo split-K partial 0 (QKV dead after each attn)
    u16* SKb  = QKV + ACT; // Wo split-K partial 1
    u16* SK0  = SKKV;      // MLP2 partial 0
    u16* SK1  = SKKV + ACT;
    (void)T2bf;

    const dim3 blk(256);

    // Unified prep (1 dispatch)
    prep_all<<<dim3(18432), blk, 0, stream>>>(
        x, key_enc, value_enc, BFx, BFK, BFV,
        Wq_m, Wk_m, Wv_m, Wq_c, Wk_c, Wv_c, Wm6,
        Wo_m, Wo_c, W1, W2, Wom_t, Woc_t, W1t, W2t);

    gemm128_proj<<<dim3(960), blk, 0, stream>>>(BFx, BFK, BFV, Wm6, QKV, KVc);

    // Self-attention; Wo_m split-K into QKV region (dead); fused ln1.
    attn_mfma_kernel<<<dim3(768), blk, 0, stream>>>(
        QKV, 3 * DD, QKV + DD, QKV + 2 * DD, 3 * DD, tgt_mask, BF1a, 1);
    gemm64_sk<<<dim3(768), blk, 0, stream>>>(BF1a, Wom_t, DD, DD / 2, SKa);
    ln_red_gen<<<MROWS, blk, 0, stream>>>(SKa, SKb, nullptr, x, nullptr,
                                          ln1_g, ln1_b, nullptr, BF1h);

    // Cross-attention: Q proj -> attn -> Wo_c split-K -> fused ln2.
    gemm64<<<dim3(384), blk, 0, stream>>>(BF1h, Wm6 + 3 * WPC, QKV, 3 * DD);
    attn_mfma_kernel<<<dim3(768), blk, 0, stream>>>(
        QKV, 3 * DD, KVc, KVc + DD, 2 * DD, src_mask, BF1a, 0);
    gemm64_sk<<<dim3(768), blk, 0, stream>>>(BF1a, Woc_t, DD, DD / 2, SKa);
    ln_red_gen<<<MROWS, blk, 0, stream>>>(SKa, SKb, nullptr, nullptr, BF1h,
                                          ln2_g, ln2_b, nullptr, BF1h);

    // MLP
    gemm128_mlp1<<<dim3(768), blk, 0, stream>>>(BF1h, W1t, b1, MID);
    gemm64_sk<<<dim3(768), blk, 0, stream>>>(MID, W2t, FF, FF / 2, SK0);
    ln_red_gen<<<MROWS, blk, 0, stream>>>(SK0, SK1, b2, nullptr, BF1h,
                                          ln3_g, ln3_b, out, nullptr);
}

// Round 35
// 240.932 us; speedup vs baseline: 1.0943x; 1.0125x over previous
//
#include <hip/hip_runtime.h>
#include <math.h>

// Problem constants
#define BB 4
#define SS 1024
#define DD 768
#define HH 12
#define DHD 64
#define MROWS 4096
#define FF 3072
#define WPC (DD * DD)

typedef unsigned short u16;
typedef float f32x4 __attribute__((ext_vector_type(4)));
typedef __bf16 bf16x8 __attribute__((ext_vector_type(8)));
typedef unsigned short u16x8 __attribute__((ext_vector_type(8)));
typedef unsigned short u16x4 __attribute__((ext_vector_type(4)));

static __device__ __forceinline__ float bf2f(u16 u) {
    union { unsigned int i; float f; } c; c.i = ((unsigned int)u) << 16; return c.f;
}
static __device__ __forceinline__ u16 f2bf(float f) {
    return __builtin_bit_cast(u16, static_cast<__bf16>(f));
}
// XCD-chunked swizzle: flat grid, total % 8 == 0.
static __device__ __forceinline__ int xcd_swz(int total) {
    const int bid = (int)blockIdx.x;
    return (bid & 7) * (total >> 3) + (bid >> 3);
}
// Async global->LDS, 16B per lane.
static __device__ __forceinline__ void gload16(const u16* g, u16* l) {
    __builtin_amdgcn_global_load_lds(
        (const __attribute__((address_space(1))) void*)g,
        (__attribute__((address_space(3))) void*)l, 16, 0, 0);
}
// GELU tanh-form via sigmoid: x*sigmoid(1.5958(x+0.044715x^3)).
// exp2-domain, hw rcp. Max abs error vs exact erf-GELU ~3e-4.
static __device__ __forceinline__ float gelu_f(float x) {
    const float x2 = x * x;
    const float t  = x * fmaf(x2, -0.10294437f, -2.30220800f);
    return x * __builtin_amdgcn_rcpf(1.0f + exp2f(t));
}

// Balanced causal q-tile map (R29-validated). Co-resident blocks on a CU are
// lids {L, L+32, L+64}; entry = qt | (B<<4); each triple sums nkt 13-14.
// XCD L2 locality preserved (R30 lesson: dynamic assignment destroys it;
// R33 lesson: divergent diag work-skip costs VGPR 80->92 / occupancy -> net
// regression — keep the inner loop branch-free and statically unrolled).
static __device__ const unsigned char QBTAB[48] = {
    15,  7,  3,
    14,  6,  2,
    31, 23,  1,
    30, 22,  0,
    47,  5, 19,
    46,  4, 18,
    13, 11, 17,
    12, 10, 16,
    29,  9, 35,
    28,  8, 34,
    45, 25, 33,
    44, 24, 32,
    27, 41, 21,
    26, 40, 20,
    43, 39, 37,
    42, 38, 36,
};

// ---------------------------------------------------------------------------
// 128x128-tile bf16 MFMA GEMM core, async staging, BK=64 dual k-half buffers.
// (BK=128 would need 64KB LDS -> occupancy loss; R32 falsified it for gemm64
// too: 49KB dropped 6->3 blocks/CU and erased the barrier savings.)
// ---------------------------------------------------------------------------
static __device__ __forceinline__ void gemm128_core(
    const u16* __restrict__ A, const u16* __restrict__ Bt,
    int K,
    const float* __restrict__ bias, int do_gelu,
    u16* __restrict__ Cbf, int ldcbf, int cboff,
    int row0, int col0, u16* As0, u16* As1, u16* Bs0, u16* Bs1)
{
    const int tid  = threadIdx.x;
    const int lane = tid & 63;
    const int w    = tid >> 6;
    const int wm = (w >> 1) * 64;
    const int wn = (w & 1) * 64;

    const u16* Ap = A  + (size_t)(row0 + w * 32 + (lane >> 2)) * K + (lane & 3) * 8;
    const u16* Bp = Bt + (size_t)(col0 + w * 32 + (lane >> 2)) * K + (lane & 3) * 8;
    const int woff = (w * 32) * 32;

    const int fr = lane & 15;
    const int fk = (lane >> 4) * 8;
    const int afo = (wm + fr) * 32 + fk;
    const int bfo = (wn + fr) * 32 + fk;

    f32x4 acc[4][4] = {};

    for (int k0 = 0; k0 < K; k0 += 64) {
        if (k0) __syncthreads();
        gload16(Ap + k0,               As0 + woff);
        gload16(Ap + k0 + 16 * K,      As0 + woff + 16 * 32);
        gload16(Ap + k0 + 32,          As1 + woff);
        gload16(Ap + k0 + 32 + 16 * K, As1 + woff + 16 * 32);
        gload16(Bp + k0,               Bs0 + woff);
        gload16(Bp + k0 + 16 * K,      Bs0 + woff + 16 * 32);
        gload16(Bp + k0 + 32,          Bs1 + woff);
        gload16(Bp + k0 + 32 + 16 * K, Bs1 + woff + 16 * 32);
        __syncthreads();

        {
            bf16x8 af[4], bfv[4];
#pragma unroll
            for (int mi = 0; mi < 4; ++mi)
                af[mi] = __builtin_bit_cast(bf16x8,
                    *(const u16x8*)(As0 + afo + mi * 16 * 32));
#pragma unroll
            for (int ni = 0; ni < 4; ++ni)
                bfv[ni] = __builtin_bit_cast(bf16x8,
                    *(const u16x8*)(Bs0 + bfo + ni * 16 * 32));
#pragma unroll
            for (int mi = 0; mi < 4; ++mi)
#pragma unroll
                for (int ni = 0; ni < 4; ++ni)
                    acc[mi][ni] = __builtin_amdgcn_mfma_f32_16x16x32_bf16(
                        af[mi], bfv[ni], acc[mi][ni], 0, 0, 0);
        }
        {
            bf16x8 af[4], bfv[4];
#pragma unroll
            for (int mi = 0; mi < 4; ++mi)
                af[mi] = __builtin_bit_cast(bf16x8,
                    *(const u16x8*)(As1 + afo + mi * 16 * 32));
#pragma unroll
            for (int ni = 0; ni < 4; ++ni)
                bfv[ni] = __builtin_bit_cast(bf16x8,
                    *(const u16x8*)(Bs1 + bfo + ni * 16 * 32));
#pragma unroll
            for (int mi = 0; mi < 4; ++mi)
#pragma unroll
                for (int ni = 0; ni < 4; ++ni)
                    acc[mi][ni] = __builtin_amdgcn_mfma_f32_16x16x32_bf16(
                        af[mi], bfv[ni], acc[mi][ni], 0, 0, 0);
        }
    }

    const int orow0 = row0 + wm + (lane >> 4) * 4;
    const int ocol0 = col0 + wn + fr;
#pragma unroll
    for (int mi = 0; mi < 4; ++mi) {
#pragma unroll
        for (int ni = 0; ni < 4; ++ni) {
            const int col = ocol0 + ni * 16;
            const float bv = bias ? bias[col] : 0.0f;
#pragma unroll
            for (int r = 0; r < 4; ++r) {
                const int row = orow0 + mi * 16 + r;
                float v = acc[mi][ni][r] + bv;
                if (do_gelu) v = gelu_f(v);
                Cbf[(size_t)row * ldcbf + cboff + col] = f2bf(v);
            }
        }
    }
}

// MLP1: flat 768-block grid, XCD-swizzled.
__global__ __launch_bounds__(256) void gemm128_mlp1(
    const u16* __restrict__ A, const u16* __restrict__ Bt,
    const float* __restrict__ bias, u16* __restrict__ Cbf)
{
    __shared__ u16 As0[128 * 32];
    __shared__ u16 As1[128 * 32];
    __shared__ u16 Bs0[128 * 32];
    __shared__ u16 Bs1[128 * 32];
    const int lid = xcd_swz(24 * 32);
    gemm128_core(A, Bt, DD, bias, 1, Cbf, FF, 0,
                 (lid / 24) * 128, (lid % 24) * 128, As0, As1, Bs0, Bs1);
}

// Batched independent projections, flat 960-block grid, XCD-swizzled.
__global__ __launch_bounds__(256) void gemm128_proj(
    const u16* __restrict__ BFx, const u16* __restrict__ BFK,
    const u16* __restrict__ BFV, const u16* __restrict__ Wm6,
    u16* __restrict__ QKV, u16* __restrict__ KVc)
{
    __shared__ u16 As0[128 * 32];
    __shared__ u16 As1[128 * 32];
    __shared__ u16 Bs0[128 * 32];
    __shared__ u16 Bs1[128 * 32];
    const int fid = xcd_swz(960);
    const u16* A; const u16* B; u16* C; int ldc, coff, row0, col0;
    if (fid < 576) {
        A = BFx; B = Wm6; C = QKV; ldc = 3 * DD; coff = 0;
        row0 = (fid / 18) * 128; col0 = (fid % 18) * 128;
    } else if (fid < 768) {
        const int l = fid - 576;
        A = BFK; B = Wm6 + 4 * WPC; C = KVc; ldc = 2 * DD; coff = 0;
        row0 = (l / 6) * 128; col0 = (l % 6) * 128;
    } else {
        const int l = fid - 768;
        A = BFV; B = Wm6 + 5 * WPC; C = KVc; ldc = 2 * DD; coff = DD;
        row0 = (l / 6) * 128; col0 = (l % 6) * 128;
    }
    gemm128_core(A, B, DD, nullptr, 0, C, ldc, coff, row0, col0,
                 As0, As1, Bs0, Bs1);
}

// ---------------------------------------------------------------------------
// 64x128-tile GEMM core, async staging, BK=64 dual k-half buffers
// (R31-exact; R32's BK=128 quad-buffer regressed via occupancy 6->3).
// ---------------------------------------------------------------------------
static __device__ __forceinline__ void gemm64_core(
    const u16* __restrict__ A, const u16* __restrict__ Bt,
    int N, int Kstride, int Klen,
    u16* __restrict__ Cbf, int ldcbf, int cboff,
    int row0, int col0, u16* As0, u16* As1, u16* Bs0, u16* Bs1)
{
    const int tid  = threadIdx.x;
    const int lane = tid & 63;
    const int w    = tid >> 6;
    const int wm = (w >> 1) * 32;
    const int wn = (w & 1) * 64;

    const u16* Ap = A  + (size_t)(row0 + w * 16 + (lane >> 2)) * Kstride + (lane & 3) * 8;
    const u16* Bp = Bt + (size_t)(col0 + w * 32 + (lane >> 2)) * Kstride + (lane & 3) * 8;
    const int aoff = (w * 16) * 32;
    const int boff = (w * 32) * 32;

    const int fr = lane & 15;
    const int fk = (lane >> 4) * 8;
    const int afo = (wm + fr) * 32 + fk;
    const int bfo = (wn + fr) * 32 + fk;

    f32x4 acc[2][4] = {};

    for (int k0 = 0; k0 < Klen; k0 += 64) {
        if (k0) __syncthreads();
        gload16(Ap + k0,                     As0 + aoff);
        gload16(Ap + k0 + 32,                As1 + aoff);
        gload16(Bp + k0,                     Bs0 + boff);
        gload16(Bp + k0 + 16 * Kstride,      Bs0 + boff + 16 * 32);
        gload16(Bp + k0 + 32,                Bs1 + boff);
        gload16(Bp + k0 + 32 + 16 * Kstride, Bs1 + boff + 16 * 32);
        __syncthreads();

        {
            bf16x8 af[2], bfv[4];
#pragma unroll
            for (int mi = 0; mi < 2; ++mi)
                af[mi] = __builtin_bit_cast(bf16x8,
                    *(const u16x8*)(As0 + afo + mi * 16 * 32));
#pragma unroll
            for (int ni = 0; ni < 4; ++ni)
                bfv[ni] = __builtin_bit_cast(bf16x8,
                    *(const u16x8*)(Bs0 + bfo + ni * 16 * 32));
#pragma unroll
            for (int mi = 0; mi < 2; ++mi)
#pragma unroll
                for (int ni = 0; ni < 4; ++ni)
                    acc[mi][ni] = __builtin_amdgcn_mfma_f32_16x16x32_bf16(
                        af[mi], bfv[ni], acc[mi][ni], 0, 0, 0);
        }
        {
            bf16x8 af[2], bfv[4];
#pragma unroll
            for (int mi = 0; mi < 2; ++mi)
                af[mi] = __builtin_bit_cast(bf16x8,
                    *(const u16x8*)(As1 + afo + mi * 16 * 32));
#pragma unroll
            for (int ni = 0; ni < 4; ++ni)
                bfv[ni] = __builtin_bit_cast(bf16x8,
                    *(const u16x8*)(Bs1 + bfo + ni * 16 * 32));
#pragma unroll
            for (int mi = 0; mi < 2; ++mi)
#pragma unroll
                for (int ni = 0; ni < 4; ++ni)
                    acc[mi][ni] = __builtin_amdgcn_mfma_f32_16x16x32_bf16(
                        af[mi], bfv[ni], acc[mi][ni], 0, 0, 0);
        }
    }

    const int orow0 = row0 + wm + (lane >> 4) * 4;
    const int ocol0 = col0 + wn + fr;
#pragma unroll
    for (int mi = 0; mi < 2; ++mi) {
#pragma unroll
        for (int ni = 0; ni < 4; ++ni) {
            const int col = ocol0 + ni * 16;
#pragma unroll
            for (int r = 0; r < 4; ++r) {
                const int row = orow0 + mi * 16 + r;
                Cbf[(size_t)row * ldcbf + cboff + col] = f2bf(acc[mi][ni][r]);
            }
        }
    }
}

// Cross-Q projection: N=K=768, output strided into QKV. 384 blocks.
__global__ __launch_bounds__(256) void gemm64(
    const u16* __restrict__ A, const u16* __restrict__ Bt,
    u16* __restrict__ Cbf, int ldcbf)
{
    __shared__ u16 As0[64 * 32];
    __shared__ u16 As1[64 * 32];
    __shared__ u16 Bs0[128 * 32];
    __shared__ u16 Bs1[128 * 32];
    const int lid = xcd_swz(6 * 64);
    gemm64_core(A, Bt, DD, DD, DD, Cbf, ldcbf, 0,
                (lid / 6) * 64, (lid % 6) * 128, As0, As1, Bs0, Bs1);
}

// Split-K x2 GEMM (Wo / MLP2): 768 blocks; bf16 partials to Cpair.
__global__ __launch_bounds__(256) void gemm64_sk(
    const u16* __restrict__ A, const u16* __restrict__ Bt,
    int Kstride, int Khalf, u16* __restrict__ Cpair)
{
    __shared__ u16 As0[64 * 32];
    __shared__ u16 As1[64 * 32];
    __shared__ u16 Bs0[128 * 32];
    __shared__ u16 Bs1[128 * 32];
    const int lid = xcd_swz(6 * 64 * 2);
    const int x = lid % 6;
    const int rem = lid / 6;
    const int y = rem % 64;
    const int z = rem / 64;
    const int koff = z * Khalf;
    gemm64_core(A + koff, Bt + koff, DD, Kstride, Khalf,
                Cpair + (size_t)z * MROWS * DD, DD, 0,
                y * 64, x * 128, As0, As1, Bs0, Bs1);
}

// ---------------------------------------------------------------------------
// Unified prep kernel (validated R20).
// ---------------------------------------------------------------------------
static __device__ __forceinline__ void tcvt_body(
    const float* __restrict__ in, u16* __restrict__ out,
    int K, int N, int bx, int by)
{
    __shared__ float t[32][33];
    const int n0 = bx * 32, k0 = by * 32;
    const int tx = threadIdx.x & 31, ty = threadIdx.x >> 5;
#pragma unroll
    for (int j = 0; j < 4; ++j)
        t[ty + j * 8][tx] = in[(size_t)(k0 + ty + j * 8) * N + n0 + tx];
    __syncthreads();
#pragma unroll
    for (int j = 0; j < 4; ++j)
        out[(size_t)(n0 + ty + j * 8) * K + k0 + tx] = f2bf(t[tx][ty + j * 8]);
}

__global__ __launch_bounds__(256) void prep_all(
    const float* __restrict__ x, const float* __restrict__ key_enc,
    const float* __restrict__ value_enc,
    u16* __restrict__ BFx, u16* __restrict__ BFK, u16* __restrict__ BFV,
    const float* __restrict__ wq_m, const float* __restrict__ wk_m,
    const float* __restrict__ wv_m, const float* __restrict__ wq_c,
    const float* __restrict__ wk_c, const float* __restrict__ wv_c,
    u16* __restrict__ Wm6,
    const float* __restrict__ wom, const float* __restrict__ woc,
    const float* __restrict__ w1, const float* __restrict__ w2,
    u16* __restrict__ womt, u16* __restrict__ woct,
    u16* __restrict__ w1t, u16* __restrict__ w2t)
{
    const int fid = (int)blockIdx.x;
    const int tid = threadIdx.x;
    if (fid < 9216) {
        const int z = fid / 3072;
        const float* s = (z == 0) ? x : (z == 1) ? key_enc : value_enc;
        u16* d = (z == 0) ? BFx : (z == 1) ? BFK : BFV;
        const int i = (fid % 3072) * 256 + tid;
        float4 v = ((const float4*)s)[i];
        ushort4 o;
        o.x = f2bf(v.x); o.y = f2bf(v.y); o.z = f2bf(v.z); o.w = f2bf(v.w);
        ((ushort4*)d)[i] = o;
    } else if (fid < 12672) {
        const int l = fid - 9216;
        const int z = l / 48;
        const int r = l % 48;
        const int wi = z / 12, head = z % 12;
        const float* wsel = (wi == 0) ? wq_m : (wi == 1) ? wk_m :
                            (wi == 2) ? wv_m : (wi == 3) ? wq_c :
                            (wi == 4) ? wk_c : wv_c;
        const float* ib = wsel + (size_t)head * DD * DHD;
        u16* ob = Wm6 + (size_t)wi * WPC + (size_t)head * DHD * DD;
        __shared__ float t[32][33];
        const int n0 = (r % 2) * 32, k0 = (r / 2) * 32;
        const int tx = tid & 31, ty = tid >> 5;
#pragma unroll
        for (int j = 0; j < 4; ++j)
            t[ty + j * 8][tx] = ib[(size_t)(k0 + ty + j * 8) * DHD + n0 + tx];
        __syncthreads();
#pragma unroll
        for (int j = 0; j < 4; ++j)
            ob[(size_t)(n0 + ty + j * 8) * DD + k0 + tx] = f2bf(t[tx][ty + j * 8]);
    } else {
        const int l = fid - 12672;
        if (l < 576) {
            tcvt_body(wom, womt, DD, DD, l % 24, l / 24);
        } else if (l < 1152) {
            const int m = l - 576;
            tcvt_body(woc, woct, DD, DD, m % 24, m / 24);
        } else if (l < 3456) {
            const int m = l - 1152;
            tcvt_body(w1, w1t, DD, FF, m % 96, m / 96);
        } else {
            const int m = l - 3456;
            tcvt_body(w2, w2t, FF, DD, m % 24, m / 24);
        }
    }
}

// ---------------------------------------------------------------------------
// MFMA flash attention (R24/R26 config) with balanced causal q-tile map:
// co-resident block triples get nkt sums 13-14 instead of worst-case 24.
// (R30 lesson: dynamic/LPT assignment destroys XCD-L2 K/V locality.
//  R33 lesson: divergent even-qt diag skip costs VGPR/occupancy > work saved.)
// ---------------------------------------------------------------------------
#define KAST 72
#define PAST 136
#define CSC 0.18033688011112042f   // 0.125 * log2(e)
__global__ __launch_bounds__(256) void attn_mfma_kernel(
    const u16* __restrict__ Q, int ldq,
    const u16* __restrict__ K, const u16* __restrict__ V, int ldkv,
    const int* __restrict__ kmask, u16* __restrict__ O, int causal)
{
    const int lid = xcd_swz(16 * BB * HH);
    int qt, bh;
    if (causal) {
        // Balanced map: chunk x (6 bh), row r (16) x half rh, third t.
        const int x   = lid / 96;
        const int l   = lid % 96;
        const int t   = l >> 5;
        const int r   = l & 31;
        const int r16 = r & 15;
        const int rh  = r >> 4;
        const unsigned int e = QBTAB[r16 * 3 + t];
        qt = (int)(e & 15u);
        bh = x * 6 + (int)(e >> 4) * 2 + rh;
    } else {
        qt = lid % 16;
        bh = lid / 16;
    }
    const int b  = bh / HH;
    const int h  = bh % HH;
    const int tid  = threadIdx.x;
    const int lane = tid & 63;
    const int w    = tid >> 6;
    const int lr = lane & 15;
    const int lg = lane >> 4;

    __shared__ u16 Ks[128 * KAST];
    __shared__ u16 Ps[64 * PAST];
    __shared__ u16 Vt[64 * PAST];

    const int row0 = qt * 64;
    const int q0w  = row0 + w * 16;

    bf16x8 qf[2];
    {
        const u16* qp = Q + (size_t)(b * SS + q0w + lr) * ldq + h * DHD + lg * 8;
        qf[0] = __builtin_bit_cast(bf16x8, *(const u16x8*)(qp));
        qf[1] = __builtin_bit_cast(bf16x8, *(const u16x8*)(qp + 32));
    }

    const int sr  = tid >> 1;
    const int scb = (tid & 1) * 32;
    const int vk  = tid >> 1;
    const int vdb = (tid & 1) * 32;
    const int k6  = vk & 63;
    const int vcol = ((vk >> 6) << 6) | ((k6 & 15) << 2) | (k6 >> 4);

    f32x4 acc[4] = {};
    float lsum[4] = {0.0f, 0.0f, 0.0f, 0.0f};

    const int nkt = causal ? ((qt + 2) >> 1) : 8;

    u16x8 kr0, kr1, kr2, kr3, vr0, vr1, vr2, vr3;
    {
        const u16* kp = K + (size_t)(b * SS + sr) * ldkv + h * DHD + scb;
        kr0 = *(const u16x8*)(kp);
        kr1 = *(const u16x8*)(kp + 8);
        kr2 = *(const u16x8*)(kp + 16);
        kr3 = *(const u16x8*)(kp + 24);
        const u16* vp = V + (size_t)(b * SS + vk) * ldkv + h * DHD + vdb;
        vr0 = *(const u16x8*)(vp);
        vr1 = *(const u16x8*)(vp + 8);
        vr2 = *(const u16x8*)(vp + 16);
        vr3 = *(const u16x8*)(vp + 24);
    }

    for (int kt = 0; kt < nkt; ++kt) {
        const int kcol0 = kt * 128;
        if (kt) __syncthreads();

        *(u16x8*)(&Ks[sr * KAST + scb])      = kr0;
        *(u16x8*)(&Ks[sr * KAST + scb + 8])  = kr1;
        *(u16x8*)(&Ks[sr * KAST + scb + 16]) = kr2;
        *(u16x8*)(&Ks[sr * KAST + scb + 24]) = kr3;
#pragma unroll
        for (int j = 0; j < 8; ++j) Vt[(vdb + j) * PAST + vcol]      = vr0[j];
#pragma unroll
        for (int j = 0; j < 8; ++j) Vt[(vdb + 8 + j) * PAST + vcol]  = vr1[j];
#pragma unroll
        for (int j = 0; j < 8; ++j) Vt[(vdb + 16 + j) * PAST + vcol] = vr2[j];
#pragma unroll
        for (int j = 0; j < 8; ++j) Vt[(vdb + 24 + j) * PAST + vcol] = vr3[j];
        __syncthreads();

        if (kt + 1 < nkt) {
            const int kn = kcol0 + 128;
            const u16* kp = K + (size_t)(b * SS + kn + sr) * ldkv + h * DHD + scb;
            kr0 = *(const u16x8*)(kp);
            kr1 = *(const u16x8*)(kp + 8);
            kr2 = *(const u16x8*)(kp + 16);
            kr3 = *(const u16x8*)(kp + 24);
            const u16* vp = V + (size_t)(b * SS + kn + vk) * ldkv + h * DHD + vdb;
            vr0 = *(const u16x8*)(vp);
            vr1 = *(const u16x8*)(vp + 8);
            vr2 = *(const u16x8*)(vp + 16);
            vr3 = *(const u16x8*)(vp + 24);
        }

        // QK^T: 8 key-groups x 2 k-steps
        f32x4 s[8] = {};
        __builtin_amdgcn_s_setprio(1);
#pragma unroll
        for (int fi = 0; fi < 8; ++fi) {
            bf16x8 kf0 = __builtin_bit_cast(bf16x8, *(const u16x8*)(&Ks[(fi * 16 + lr) * KAST + lg * 8]));
            bf16x8 kf1 = __builtin_bit_cast(bf16x8, *(const u16x8*)(&Ks[(fi * 16 + lr) * KAST + 32 + lg * 8]));
            s[fi] = __builtin_amdgcn_mfma_f32_16x16x32_bf16(qf[0], kf0, s[fi], 0, 0, 0);
            s[fi] = __builtin_amdgcn_mfma_f32_16x16x32_bf16(qf[1], kf1, s[fi], 0, 0, 0);
        }
        __builtin_amdgcn_s_setprio(0);

        float biasf[8];
#pragma unroll
        for (int fi = 0; fi < 8; ++fi)
            biasf[fi] = kmask[b * SS + kcol0 + fi * 16 + lr] ? 0.0f : -INFINITY;
        const bool diag = (causal != 0) && (kt == nkt - 1);

#pragma unroll
        for (int r = 0; r < 4; ++r) {
            const int qrow = q0w + lg * 4 + r;
            const int prow = (w * 16 + lg * 4 + r) * PAST;
            u16x4 pk0, pk1;
            float rs = 0.0f;
#pragma unroll
            for (int fi = 0; fi < 8; ++fi) {
                float v = fmaf(s[fi][r], CSC, biasf[fi]);
                if (diag) {
                    const int key = kcol0 + fi * 16 + lr;
                    v = (key <= qrow) ? v : -INFINITY;
                }
                const float pv = exp2f(v);
                if (fi < 4) pk0[fi] = f2bf(pv); else pk1[fi - 4] = f2bf(pv);
                rs += pv;
            }
            lsum[r] += rs;
            *(u16x4*)(&Ps[prow + lr * 4])      = pk0;
            *(u16x4*)(&Ps[prow + 64 + lr * 4]) = pk1;
        }

        // PV
        __builtin_amdgcn_s_setprio(1);
#pragma unroll
        for (int kk = 0; kk < 4; ++kk) {
            bf16x8 pf = __builtin_bit_cast(bf16x8, *(const u16x8*)(&Ps[(w * 16 + lr) * PAST + kk * 32 + lg * 8]));
#pragma unroll
            for (int di = 0; di < 4; ++di) {
                bf16x8 vf = __builtin_bit_cast(bf16x8, *(const u16x8*)(&Vt[(di * 16 + lr) * PAST + kk * 32 + lg * 8]));
                acc[di] = __builtin_amdgcn_mfma_f32_16x16x32_bf16(pf, vf, acc[di], 0, 0, 0);
            }
        }
        __builtin_amdgcn_s_setprio(0);
    }

#pragma unroll
    for (int r = 0; r < 4; ++r) {
        float l = lsum[r];
        l += __shfl_xor(l, 1);
        l += __shfl_xor(l, 2);
        l += __shfl_xor(l, 4);
        l += __shfl_xor(l, 8);
        const float inv = (l > 0.0f) ? (1.0f / l) : 0.0f;
        const size_t orow = (size_t)(b * SS + q0w + lg * 4 + r) * DD + h * DHD;
#pragma unroll
        for (int di = 0; di < 4; ++di)
            O[orow + di * 16 + lr] = f2bf(acc[di][r] * inv);
    }
}

// ---------------------------------------------------------------------------
// Generic LayerNorm over (P0 + P1 [+ bias] [+ residf32 | residb16]) ->
// optional fp32 and/or bf16 outputs. Single-pass: sum & sumsq accumulated
// together (var = E[x^2] - mean^2), wave shfl reduction -> ONE barrier
// (was 17 barriers across two tree reductions).
// ---------------------------------------------------------------------------
__global__ __launch_bounds__(256) void ln_red_gen(
    const u16* __restrict__ P0, const u16* __restrict__ P1,
    const float* __restrict__ bias,
    const float* __restrict__ residf, const u16* __restrict__ residb,
    const float* __restrict__ gma, const float* __restrict__ bta,
    float* __restrict__ Yf, u16* __restrict__ Ybf)
{
    const int row = blockIdx.x;
    const int tid = threadIdx.x;
    const size_t base = (size_t)row * DD;

    float v[3];
    float s = 0.0f, s2 = 0.0f;
#pragma unroll
    for (int j = 0; j < 3; ++j) {
        const int i = tid + j * 256;
        float t = bf2f(P0[base + i]) + bf2f(P1[base + i]);
        if (bias)   t += bias[i];
        if (residf) t += residf[base + i];
        if (residb) t += bf2f(residb[base + i]);
        v[j] = t;
        s  += t;
        s2 += t * t;
    }

    // Wave-level butterfly reduce (64 lanes), both accumulators.
#pragma unroll
    for (int off = 1; off < 64; off <<= 1) {
        s  += __shfl_xor(s,  off);
        s2 += __shfl_xor(s2, off);
    }
    __shared__ float sw[8];
    const int wv = tid >> 6;
    if ((tid & 63) == 0) { sw[wv] = s; sw[4 + wv] = s2; }
    __syncthreads();
    const float S  = sw[0] + sw[1] + sw[2] + sw[3];
    const float S2 = sw[4] + sw[5] + sw[6] + sw[7];

    const float mean = S * (1.0f / 768.0f);
    const float var  = S2 * (1.0f / 768.0f) - mean * mean;
    const float inv  = rsqrtf(var + 1e-5f);

#pragma unroll
    for (int j = 0; j < 3; ++j) {
        const int i = tid + j * 256;
        const float y = (v[j] - mean) * inv * gma[i] + bta[i];
        if (Yf)  Yf[base + i] = y;
        if (Ybf) Ybf[base + i] = f2bf(y);
    }
}

// ---------------------------------------------------------------------------
extern "C" void kernel_launch(void* const* d_in, const int* in_sizes, int n_in,
                              void* d_out, int out_size, void* d_ws, size_t ws_size,
                              hipStream_t stream)
{
    (void)in_sizes; (void)n_in; (void)out_size; (void)ws_size;

    const float* key_enc   = (const float*)d_in[0];
    const float* value_enc = (const float*)d_in[1];
    const float* x         = (const float*)d_in[2];
    const int*   src_mask  = (const int*)d_in[3];
    const int*   tgt_mask  = (const int*)d_in[4];
    const float* Wq_m = (const float*)d_in[5];
    const float* Wk_m = (const float*)d_in[6];
    const float* Wv_m = (const float*)d_in[7];
    const float* Wo_m = (const float*)d_in[8];
    const float* Wq_c = (const float*)d_in[9];
    const float* Wk_c = (const float*)d_in[10];
    const float* Wv_c = (const float*)d_in[11];
    const float* Wo_c = (const float*)d_in[12];
    const float* ln1_g = (const float*)d_in[13];
    const float* ln1_b = (const float*)d_in[14];
    const float* ln2_g = (const float*)d_in[15];
    const float* ln2_b = (const float*)d_in[16];
    const float* ln3_g = (const float*)d_in[17];
    const float* ln3_b = (const float*)d_in[18];
    const float* W1 = (const float*)d_in[19];
    const float* b1 = (const float*)d_in[20];
    const float* W2 = (const float*)d_in[21];
    const float* b2 = (const float*)d_in[22];

    float* out = (float*)d_out;

    // workspace layout
    const size_t ACT = (size_t)MROWS * DD;
    char* p = (char*)d_ws;
    u16* QKV  = (u16*)p;   p += 3 * ACT * 2;
    u16* BFx  = (u16*)p;   p += ACT * 2;
    u16* BFK  = (u16*)p;   p += ACT * 2;
    u16* BFV  = (u16*)p;   p += ACT * 2;
    u16* BF1a = (u16*)p;   p += ACT * 2;
    u16* BF1h = (u16*)p;   p += ACT * 2;
    u16* T2bf = (u16*)p;   p += ACT * 2;           // spare
    u16* SKKV = (u16*)p;   p += 2 * ACT * 2;       // cross-KV | MLP2 partials
    u16* Wm6  = (u16*)p;   p += 6 * (size_t)WPC * 2;
    u16* Wom_t = (u16*)p;  p += (size_t)WPC * 2;
    u16* Woc_t = (u16*)p;  p += (size_t)WPC * 2;
    u16* W1t  = (u16*)p;   p += (size_t)DD * FF * 2;
    u16* W2t  = (u16*)p;   p += (size_t)DD * FF * 2;
    u16* MID  = QKV;       // [4096][3072] aliases QKV+BFx (dead by MLP)
    u16* KVc  = SKKV;      // cross K|V (dead by MLP2)
    u16* SKa  = QKV;       // Wo split-K partial 0 (QKV dead after each attn)
    u16* SKb  = QKV + ACT; // Wo split-K partial 1
    u16* SK0  = SKKV;      // MLP2 partial 0
    u16* SK1  = SKKV + ACT;
    (void)T2bf;

    const dim3 blk(256);

    // Unified prep (1 dispatch)
    prep_all<<<dim3(18432), blk, 0, stream>>>(
        x, key_enc, value_enc, BFx, BFK, BFV,
        Wq_m, Wk_m, Wv_m, Wq_c, Wk_c, Wv_c, Wm6,
        Wo_m, Wo_c, W1, W2, Wom_t, Woc_t, W1t, W2t);

    gemm128_proj<<<dim3(960), blk, 0, stream>>>(BFx, BFK, BFV, Wm6, QKV, KVc);

    // Self-attention; Wo_m split-K into QKV region (dead); fused ln1.
    attn_mfma_kernel<<<dim3(768), blk, 0, stream>>>(
        QKV, 3 * DD, QKV + DD, QKV + 2 * DD, 3 * DD, tgt_mask, BF1a, 1);
    gemm64_sk<<<dim3(768), blk, 0, stream>>>(BF1a, Wom_t, DD, DD / 2, SKa);
    ln_red_gen<<<MROWS, blk, 0, stream>>>(SKa, SKb, nullptr, x, nullptr,
                                          ln1_g, ln1_b, nullptr, BF1h);

    // Cross-attention: Q proj -> attn -> Wo_c split-K -> fused ln2.
    gemm64<<<dim3(384), blk, 0, stream>>>(BF1h, Wm6 + 3 * WPC, QKV, 3 * DD);
    attn_mfma_kernel<<<dim3(768), blk, 0, stream>>>(
        QKV, 3 * DD, KVc, KVc + DD, 2 * DD, src_mask, BF1a, 0);
    gemm64_sk<<<dim3(768), blk, 0, stream>>>(BF1a, Woc_t, DD, DD / 2, SKa);
    ln_red_gen<<<MROWS, blk, 0, stream>>>(SKa, SKb, nullptr, nullptr, BF1h,
                                          ln2_g, ln2_b, nullptr, BF1h);

    // MLP
    gemm128_mlp1<<<dim3(768), blk, 0, stream>>>(BF1h, W1t, b1, MID);
    gemm64_sk<<<dim3(768), blk, 0, stream>>>(MID, W2t, FF, FF / 2, SK0);
    ln_red_gen<<<MROWS, blk, 0, stream>>>(SK0, SK1, b2, nullptr, BF1h,
                                          ln3_g, ln3_b, out, nullptr);
}